// Round 6
// baseline (218.298 us; speedup 1.0000x reference)
//
#include <hip/hip_runtime.h>
#include <hip/hip_bf16.h>
#include <cstdint>

// MultiHeadSelfAttention N=2,L=2048,E=1024,H=16,D=64.
// Round 10: attn q-reuse x2 + split-K. Block = 512 thr = 8 waves =
// 4 q-groups (64 q each: subtiles a/b share every kf/vf LDS read -> LDS
// read traffic halved) x 2 k-halves (16 tiles each). Grid 256 XCD-grouped,
// 1 block/CU, 2 waves/SIMD. Double-buffered XOR-swizzled K/V LDS per half,
// register prefetch 2 tiles ahead, 2 barriers/tile (16 tiles). In-register
// softmax; a/b structure gives QK||SM||PV ILP without St double-state.
// Split-K merge via 2 LDS rounds (r2-verified). Mask-at-source + nmask.
// NOTE: SQ_LDS_BANK_CONFLICT == +4cy/b128 read inherent (2^22 == 4*2^20
// exactly, layout-independent) -- not a fixable conflict; don't chase it.
// proj/outproj byte-identical to round 9 for attribution.

#define NB 2
#define LSEQ 2048
#define EMB 1024
#define NHEADS 16
#define HD 64

// (1/sqrt(1024)) * log2(e): folded into Q projection output; P = exp2(S)
#define QSCALE 0.045084220027780106f

using short8 = __attribute__((ext_vector_type(8))) short;
using short4v = __attribute__((ext_vector_type(4))) short;
using f32x4 = __attribute__((ext_vector_type(4))) float;
using f32x16 = __attribute__((ext_vector_type(16))) float;
using uint2v = __attribute__((ext_vector_type(2))) unsigned int;

__device__ inline short bf16of(float f) {
  union { __hip_bfloat16 b; short s; } u;
  u.b = __float2bfloat16(f);
  return u.s;
}

__device__ inline short4v pack4bf(float a, float b, float c, float d) {
  union { __hip_bfloat162 v[2]; short4v s; } u;
  u.v[0] = __float22bfloat162_rn(make_float2(a, b));
  u.v[1] = __float22bfloat162_rn(make_float2(c, d));
  return u.s;
}

__device__ inline short8 pack8bf(float4 a, float4 b) {
  union { short4v q[2]; short8 o; } u;
  u.q[0] = pack4bf(a.x, a.y, a.z, a.w);
  u.q[1] = pack4bf(b.x, b.y, b.z, b.w);
  return u.o;
}

__device__ inline unsigned pk2(float lo, float hi) {
  union { __hip_bfloat162 v; unsigned u; } x;
  x.v = __float22bfloat162_rn(make_float2(lo, hi));
  return x.u;
}

// v_permlane32_swap_b32: a' = {a.lo, b.lo}, b' = {a.hi, b.hi}
__device__ inline void plswap(unsigned& a, unsigned& b) {
#if __has_builtin(__builtin_amdgcn_permlane32_swap)
  uint2v r = __builtin_amdgcn_permlane32_swap(a, b, false, false);
  a = r[0];
  b = r[1];
#else
  asm volatile("v_permlane32_swap_b32 %0, %1" : "+v"(a), "+v"(b));
#endif
}

__device__ inline float fexp2(float x) {
#if __has_builtin(__builtin_amdgcn_exp2f)
  return __builtin_amdgcn_exp2f(x);
#else
  return exp2f(x);
#endif
}

#define MFMA(A, B, C) __builtin_amdgcn_mfma_f32_16x16x32_bf16((A), (B), (C), 0, 0, 0)
#define MFMA32(A, B, C) __builtin_amdgcn_mfma_f32_32x32x16_bf16((A), (B), (C), 0, 0, 0)

// ---------------------------------------------------------------------------
// LDS-free MFMA projections, W converted f32->bf16 in-register. Block = 4
// waves, 64 l-rows, one (n,h,z). z==0 (Q): output scaled by QSCALE.
// z==1 (K): masked rows zeroed. z==2 (V): masked V^T cols zeroed.
__global__ __launch_bounds__(256) void proj_mfma(
    const float* __restrict__ xq, const float* __restrict__ xk,
    const float* __restrict__ xv, const float* __restrict__ Wq,
    const float* __restrict__ Wk, const float* __restrict__ Wv,
    const int* __restrict__ mask, short* __restrict__ Qb,
    short* __restrict__ Kb, short* __restrict__ Vt) {
  const int t = threadIdx.x;
  const int wq = t >> 6, lane = t & 63;
  const int quad = lane >> 4, l15 = lane & 15;
  const int z = blockIdx.z, nh = blockIdx.y;
  const int n = nh >> 4, h = nh & 15;
  const int l0 = blockIdx.x * 64;
  const float* x = (z == 0) ? xq : (z == 1) ? xk : xv;
  const float* W = (z == 0) ? Wq : (z == 1) ? Wk : Wv;
  const int lrow = l0 + wq * 16 + l15;  // this lane's l (n-index for z<2)

  // x fragment: 8 f32 -> bf16, k = e chunk c*32+quad*8
  short8 xf[2];
  const float* xr = x + ((size_t)n * LSEQ + lrow) * EMB + h * HD;
#pragma unroll
  for (int c = 0; c < 2; ++c) {
    float4 a = *(const float4*)(xr + c * 32 + quad * 8);
    float4 b = *(const float4*)(xr + c * 32 + quad * 8 + 4);
    xf[c] = pack8bf(a, b);
  }
  // W fragments from f32: row (mt*16+l15) of W[d][e]
  short8 wf[4][2];
#pragma unroll
  for (int mt = 0; mt < 4; ++mt)
#pragma unroll
    for (int c = 0; c < 2; ++c) {
      const float* wr = W + (mt * 16 + l15) * HD + c * 32 + quad * 8;
      wf[mt][c] = pack8bf(*(const float4*)wr, *(const float4*)(wr + 4));
    }

  f32x4 acc[4];
#pragma unroll
  for (int a = 0; a < 4; ++a) acc[a] = (f32x4){0.f, 0.f, 0.f, 0.f};

  if (z < 2) {
#pragma unroll
    for (int c = 0; c < 2; ++c)
#pragma unroll
      for (int mt = 0; mt < 4; ++mt) acc[mt] = MFMA(wf[mt][c], xf[c], acc[mt]);
    // Q: fold QSCALE; K: zero masked rows at the source
    const float mk =
        (z == 0) ? QSCALE : (mask[n * LSEQ + lrow] ? 1.0f : 0.0f);
    short* ob = ((z == 0) ? Qb : Kb) + ((size_t)nh * LSEQ + lrow) * HD;
#pragma unroll
    for (int mt = 0; mt < 4; ++mt)
      *(short4v*)&ob[mt * 16 + quad * 4] =
          pack4bf(acc[mt][0] * mk, acc[mt][1] * mk, acc[mt][2] * mk,
                  acc[mt][3] * mk);
  } else {
#pragma unroll
    for (int c = 0; c < 2; ++c)
#pragma unroll
      for (int nt = 0; nt < 4; ++nt) acc[nt] = MFMA(xf[c], wf[nt][c], acc[nt]);
    // C rows = l = l0 + wq*16 + quad*4 + r ; cols = d = nt*16+l15
    const int4 mi = *(const int4*)(mask + n * LSEQ + l0 + wq * 16 + quad * 4);
    f32x4 mv;
    mv[0] = mi.x ? 1.f : 0.f;
    mv[1] = mi.y ? 1.f : 0.f;
    mv[2] = mi.z ? 1.f : 0.f;
    mv[3] = mi.w ? 1.f : 0.f;
#pragma unroll
    for (int nt = 0; nt < 4; ++nt)
      *(short4v*)&Vt[((size_t)nh * HD + nt * 16 + l15) * LSEQ + l0 + wq * 16 +
                     quad * 4] =
          pack4bf(acc[nt][0] * mv[0], acc[nt][1] * mv[1], acc[nt][2] * mv[2],
                  acc[nt][3] * mv[3]);
  }
}

// ---------------------------------------------------------------------------
// Flash attention, 32x32 MFMA, q-reuse x2 + split-K.
// Block = 512 threads = 8 waves: qg = wv&3 (owns 64 q as subtiles a/b),
// kh = wv>>2 (k half, 16 tiles). Grid 256 XCD-grouped -> 1 block/CU,
// 2 waves/SIMD. Each kf/vf LDS read feeds BOTH subtiles (2 MFMAs) -> LDS
// read traffic halved vs r9. Double-buffered XOR-swizzled K/V LDS per half;
// register prefetch 2 tiles ahead; 2 barriers per tile. Masked K rows /
// V cols zero at source -> masked P == 1; l corrected by nmask.
// Split-K merge: 2 LDS rounds (O_a then O_b), kh==0 waves write output.
__global__ __launch_bounds__(512, 2) void attn_kernel(
    const short* __restrict__ Qg,   // [nh][L][64] bf16 (Wq pre-scaled)
    const short* __restrict__ Kg,   // [nh][L][64] bf16 (masked rows zero)
    const short* __restrict__ Vtg,  // [nh][64][L] bf16 (masked cols zero)
    const int* __restrict__ mask,   // [N][L]
    short* __restrict__ AO)         // [N*L][E] bf16
{
  __shared__ __align__(16) short Ks[2][2][64 * 64];  // [kh][buf] 32KB
  __shared__ __align__(16) short Vs[2][2][64 * 64];  // 32KB
  __shared__ __align__(16) float xch[4][64 * 35];    // merge, 35.8KB

  const int t = threadIdx.x;
  const int wv = t >> 6, lane = t & 63;
  const int l31 = lane & 31, hi = lane >> 5;
  const int qg = wv & 3, kh = wv >> 2;

  // XCD-grouped: 256 blocks, 32/XCD; nh = xcd*4 + (idx>>3), q0 = (idx&7)*256
  const int raw = blockIdx.x;
  const int xcd = raw & 7, idx = raw >> 3;
  const int nh = (xcd << 2) | (idx >> 3);
  const int q0 = (idx & 7) * 256;
  const int n = nh >> 4, h = nh & 15;

  // nmask: count of masked (==0) keys for this n (per-wave redundant)
  float nm = 0.f;
  {
    const int* mp = mask + n * LSEQ + lane * 32;
#pragma unroll
    for (int i = 0; i < 8; ++i) {
      int4 m = *(const int4*)(mp + i * 4);
      nm += (float)((m.x == 0) + (m.y == 0) + (m.z == 0) + (m.w == 0));
    }
#pragma unroll
    for (int o = 1; o < 64; o <<= 1) nm += __shfl_xor(nm, o);
  }

  // Q B-fragments for subtiles a (q0+qg*64+l31) and b (+32)
  short8 qfa[4], qfb[4];
  {
    const short* qra =
        Qg + ((size_t)nh * LSEQ + q0 + qg * 64 + l31) * HD + hi * 8;
    const short* qrb = qra + 32 * HD;
#pragma unroll
    for (int s = 0; s < 4; ++s) {
      qfa[s] = *(const short8*)(qra + s * 16);
      qfb[s] = *(const short8*)(qrb + s * 16);
    }
  }

  const short* kbase = Kg + ((size_t)nh * LSEQ + kh * (LSEQ / 2)) * HD;
  const short* vbase = Vtg + (size_t)nh * HD * LSEQ + kh * (LSEQ / 2);

  // staging: per half, 256 threads cover 512 16B slots (rows ts>>3, +32)
  const int ts = t & 255;
  const int r0s = ts >> 3, cs = ts & 7, r1s = r0s + 32;
  const int ld0 = r0s * 64 + ((cs ^ (r0s & 7)) * 8);
  const int ld1 = r1s * 64 + ((cs ^ (r1s & 7)) * 8);

  // prologue: stage this half's tiles 0 and 1
#pragma unroll
  for (int pt = 0; pt < 2; ++pt) {
    const short* kb = kbase + (size_t)pt * 64 * HD;
    const short* vb = vbase + pt * 64;
    short8 k0 = *(const short8*)(kb + (size_t)r0s * HD + cs * 8);
    short8 k1 = *(const short8*)(kb + (size_t)r1s * HD + cs * 8);
    short8 v0 = *(const short8*)(vb + (size_t)r0s * LSEQ + cs * 8);
    short8 v1 = *(const short8*)(vb + (size_t)r1s * LSEQ + cs * 8);
    *(short8*)&Ks[kh][pt][ld0] = k0;
    *(short8*)&Ks[kh][pt][ld1] = k1;
    *(short8*)&Vs[kh][pt][ld0] = v0;
    *(short8*)&Vs[kh][pt][ld1] = v1;
  }
  __syncthreads();

  f32x16 Oa[2], Ob[2];
#pragma unroll
  for (int nt = 0; nt < 2; ++nt)
#pragma unroll
    for (int r = 0; r < 16; ++r) {
      Oa[nt][r] = 0.f;
      Ob[nt][r] = 0.f;
    }
  float lsa[4] = {0.f, 0.f, 0.f, 0.f};
  float lsb[4] = {0.f, 0.f, 0.f, 0.f};

#pragma unroll 1
  for (int it = 0; it < 16; ++it) {
    const bool haveLd = it < 14;
    short8 kr0, kr1, vr0, vr1;
    if (haveLd) {
      const short* kb = kbase + (size_t)(it + 2) * 64 * HD;
      const short* vb = vbase + (it + 2) * 64;
      kr0 = *(const short8*)(kb + (size_t)r0s * HD + cs * 8);
      kr1 = *(const short8*)(kb + (size_t)r1s * HD + cs * 8);
      vr0 = *(const short8*)(vb + (size_t)r0s * LSEQ + cs * 8);
      vr1 = *(const short8*)(vb + (size_t)r1s * LSEQ + cs * 8);
    }
    const short* ksb = &Ks[kh][it & 1][0];
    const short* vsb = &Vs[kh][it & 1][0];

    // ---- QK both subtiles; each kf read feeds 2 MFMAs
    f32x16 Sa[2], Sb[2];
#pragma unroll
    for (int g = 0; g < 2; ++g)
#pragma unroll
      for (int r = 0; r < 16; ++r) {
        Sa[g][r] = 0.f;
        Sb[g][r] = 0.f;
      }
    __builtin_amdgcn_s_setprio(1);
#pragma unroll
    for (int g = 0; g < 2; ++g) {
      const int row = g * 32 + l31;
      const int rb = row * 64, sx = row & 7;
#pragma unroll
      for (int s = 0; s < 4; ++s) {
        short8 kf = *(const short8*)(ksb + rb + (((s * 2 + hi) ^ sx) * 8));
        Sa[g] = MFMA32(kf, qfa[s], Sa[g]);
        Sb[g] = MFMA32(kf, qfb[s], Sb[g]);
      }
    }
    __builtin_amdgcn_s_setprio(0);

    // ---- SM a: P = exp2(S); row-sum; repack -> A-fragments
    short8 paa[4];
#pragma unroll
    for (int g = 0; g < 2; ++g) {
#pragma unroll
      for (int r = 0; r < 16; ++r) {
        float e = fexp2(Sa[g][r]);
        Sa[g][r] = e;
        lsa[r & 3] += e;
      }
#pragma unroll
      for (int hf = 0; hf < 2; ++hf) {
        unsigned w0 = pk2(Sa[g][hf * 8 + 0], Sa[g][hf * 8 + 1]);
        unsigned w2 = pk2(Sa[g][hf * 8 + 4], Sa[g][hf * 8 + 5]);
        plswap(w0, w2);
        unsigned w1 = pk2(Sa[g][hf * 8 + 2], Sa[g][hf * 8 + 3]);
        unsigned w3 = pk2(Sa[g][hf * 8 + 6], Sa[g][hf * 8 + 7]);
        plswap(w1, w3);
        union { unsigned u[4]; short8 s; } uo;
        uo.u[0] = w0;
        uo.u[1] = w1;
        uo.u[2] = w2;
        uo.u[3] = w3;
        paa[g * 2 + hf] = uo.s;
      }
    }

    // ---- V fragments (shared by both subtiles); latency hides under SM b
    short8 vf[8];
#pragma unroll
    for (int s = 0; s < 4; ++s)
#pragma unroll
      for (int nt = 0; nt < 2; ++nt) {
        const int row = nt * 32 + l31;
        vf[s * 2 + nt] = *(const short8*)(vsb + row * 64 +
                                          (((s * 2 + hi) ^ (row & 7)) * 8));
      }

    // ---- SM b
    short8 pab[4];
#pragma unroll
    for (int g = 0; g < 2; ++g) {
#pragma unroll
      for (int r = 0; r < 16; ++r) {
        float e = fexp2(Sb[g][r]);
        Sb[g][r] = e;
        lsb[r & 3] += e;
      }
#pragma unroll
      for (int hf = 0; hf < 2; ++hf) {
        unsigned w0 = pk2(Sb[g][hf * 8 + 0], Sb[g][hf * 8 + 1]);
        unsigned w2 = pk2(Sb[g][hf * 8 + 4], Sb[g][hf * 8 + 5]);
        plswap(w0, w2);
        unsigned w1 = pk2(Sb[g][hf * 8 + 2], Sb[g][hf * 8 + 3]);
        unsigned w3 = pk2(Sb[g][hf * 8 + 6], Sb[g][hf * 8 + 7]);
        plswap(w1, w3);
        union { unsigned u[4]; short8 s; } uo;
        uo.u[0] = w0;
        uo.u[1] = w1;
        uo.u[2] = w2;
        uo.u[3] = w3;
        pab[g * 2 + hf] = uo.s;
      }
    }

    // ---- PV both subtiles; each vf feeds 2 MFMAs
    __builtin_amdgcn_s_setprio(1);
#pragma unroll
    for (int s = 0; s < 4; ++s) {
      Oa[0] = MFMA32(paa[s], vf[2 * s], Oa[0]);
      Oa[1] = MFMA32(paa[s], vf[2 * s + 1], Oa[1]);
      Ob[0] = MFMA32(pab[s], vf[2 * s], Ob[0]);
      Ob[1] = MFMA32(pab[s], vf[2 * s + 1], Ob[1]);
    }
    __builtin_amdgcn_s_setprio(0);

    // ---- recycle buffer (it&1) with tile it+2
    if (haveLd) {
      __syncthreads();  // all 4 q-waves of this half done reading buf
      short* kd = &Ks[kh][it & 1][0];
      short* vd = &Vs[kh][it & 1][0];
      *(short8*)&kd[ld0] = kr0;
      *(short8*)&kd[ld1] = kr1;
      *(short8*)&vd[ld0] = vr0;
      *(short8*)&vd[ld1] = vr1;
      __syncthreads();
    }
  }

  // ---- split-K merge (2 rounds through xch), then kh==0 writes
  float la = (lsa[0] + lsa[1]) + (lsa[2] + lsa[3]);
  la += __shfl_xor(la, 32);
  float lb = (lsb[0] + lsb[1]) + (lsb[2] + lsb[3]);
  lb += __shfl_xor(lb, 32);

  float* xb = &xch[qg][lane * 35];
  // round A
  if (kh == 1) {
#pragma unroll
    for (int nt = 0; nt < 2; ++nt)
#pragma unroll
      for (int c = 0; c < 4; ++c) {
        f32x4 v;
#pragma unroll
        for (int j = 0; j < 4; ++j) v[j] = Oa[nt][c * 4 + j];
        *(f32x4*)(xb + (nt * 4 + c) * 4) = v;
      }
    xb[32] = la;
  }
  __syncthreads();
  if (kh == 0) {
#pragma unroll
    for (int nt = 0; nt < 2; ++nt)
#pragma unroll
      for (int c = 0; c < 4; ++c) {
        f32x4 p = *(const f32x4*)(xb + (nt * 4 + c) * 4);
#pragma unroll
        for (int j = 0; j < 4; ++j) Oa[nt][c * 4 + j] += p[j];
      }
    la = la + xb[32] - nm;  // masked keys contributed exp2(0)=1 each
  }
  __syncthreads();
  // round B
  if (kh == 1) {
#pragma unroll
    for (int nt = 0; nt < 2; ++nt)
#pragma unroll
      for (int c = 0; c < 4; ++c) {
        f32x4 v;
#pragma unroll
        for (int j = 0; j < 4; ++j) v[j] = Ob[nt][c * 4 + j];
        *(f32x4*)(xb + (nt * 4 + c) * 4) = v;
      }
    xb[32] = lb;
  }
  __syncthreads();
  if (kh == 0) {
#pragma unroll
    for (int nt = 0; nt < 2; ++nt)
#pragma unroll
      for (int c = 0; c < 4; ++c) {
        f32x4 p = *(const f32x4*)(xb + (nt * 4 + c) * 4);
#pragma unroll
        for (int j = 0; j < 4; ++j) Ob[nt][c * 4 + j] += p[j];
      }
    lb = lb + xb[32] - nm;

    // ---- epilogue: O/l -> bf16 AO[n*L + q][h*64 + dv]
    const float linva = 1.0f / la;
    const float linvb = 1.0f / lb;
    short* ob = AO + ((size_t)n * LSEQ + q0 + qg * 64) * EMB + h * HD;
#pragma unroll
    for (int r = 0; r < 16; ++r) {
      const int qr = (r & 3) + 8 * (r >> 2) + 4 * hi;
      float lia = __int_as_float(
          __builtin_amdgcn_ds_bpermute(qr << 2, __float_as_int(linva)));
      float lib = __int_as_float(
          __builtin_amdgcn_ds_bpermute(qr << 2, __float_as_int(linvb)));
      ob[(size_t)qr * EMB + l31] = bf16of(Oa[0][r] * lia);
      ob[(size_t)qr * EMB + 32 + l31] = bf16of(Oa[1][r] * lia);
      ob[(size_t)(qr + 32) * EMB + l31] = bf16of(Ob[0][r] * lib);
      ob[(size_t)(qr + 32) * EMB + 32 + l31] = bf16of(Ob[1][r] * lib);
    }
  }
}

// ---------------------------------------------------------------------------
// Out-projection: C[r][j] = sum_e A[r][e]*Wo[j][e] + bo[j]. Wo converted
// f32->bf16 during staging. 128x64 tile/block, grid 512, XCD-grouped by
// r-block. XOR-swizzled LDS, double-buffered, register prefetch.
__global__ __launch_bounds__(256, 2) void outproj_mfma(
    const short* __restrict__ A, const float* __restrict__ Wo,
    const float* __restrict__ bo, float* __restrict__ C) {
  __shared__ __align__(16) short As[2][128 * 64];
  __shared__ __align__(16) short Bs[2][64 * 64];
  const int t = threadIdx.x;
  const int wq = t >> 6, lane = t & 63;
  const int quad = lane >> 4, l15 = lane & 15;
  // XCD-grouped: 512 blocks, 64/XCD; ry = xcd*4 + (idx>>4), jx = idx&15.
  const int raw = blockIdx.x;
  const int xcd = raw & 7, idx = raw >> 3;
  const int ry = (xcd << 2) | (idx >> 4);
  const int j0 = (idx & 15) * 64, r0 = ry * 128;

  f32x4 acc[2][4];
#pragma unroll
  for (int a = 0; a < 2; ++a)
#pragma unroll
    for (int b = 0; b < 4; ++b) acc[a][b] = (f32x4){0.f, 0.f, 0.f, 0.f};

  // A: 1024 slots (row = slot>>3, ch = slot&7); B: 512 slots.
  short8 ar[4], br[2];
#pragma unroll
  for (int i = 0; i < 4; ++i) {
    int slot = i * 256 + t, row = slot >> 3, ch = slot & 7;
    ar[i] = *(const short8*)(A + (size_t)(r0 + row) * EMB + ch * 8);
  }
#pragma unroll
  for (int i = 0; i < 2; ++i) {
    int slot = i * 256 + t, row = slot >> 3, ch = slot & 7;
    const float* wr = Wo + (size_t)(j0 + row) * EMB + ch * 8;
    br[i] = pack8bf(*(const float4*)wr, *(const float4*)(wr + 4));
  }
#pragma unroll
  for (int i = 0; i < 4; ++i) {
    int slot = i * 256 + t, row = slot >> 3, ch = slot & 7;
    *(short8*)&As[0][row * 64 + ((ch ^ (row & 7)) * 8)] = ar[i];
  }
#pragma unroll
  for (int i = 0; i < 2; ++i) {
    int slot = i * 256 + t, row = slot >> 3, ch = slot & 7;
    *(short8*)&Bs[0][row * 64 + ((ch ^ (row & 7)) * 8)] = br[i];
  }
  __syncthreads();

  const int sw0 = ((0 * 4 + quad) ^ (l15 & 7)) * 8;
  const int sw1 = ((1 * 4 + quad) ^ (l15 & 7)) * 8;

  for (int ek = 0; ek < EMB; ek += 64) {
    const int cur = (ek >> 6) & 1, nxt = cur ^ 1;
    if (ek + 64 < EMB) {
#pragma unroll
      for (int i = 0; i < 4; ++i) {
        int slot = i * 256 + t, row = slot >> 3, ch = slot & 7;
        ar[i] = *(const short8*)(A + (size_t)(r0 + row) * EMB + ek + 64 + ch * 8);
      }
#pragma unroll
      for (int i = 0; i < 2; ++i) {
        int slot = i * 256 + t, row = slot >> 3, ch = slot & 7;
        const float* wr = Wo + (size_t)(j0 + row) * EMB + ek + 64 + ch * 8;
        br[i] = pack8bf(*(const float4*)wr, *(const float4*)(wr + 4));
      }
    }
#pragma unroll
    for (int c = 0; c < 2; ++c) {
      const int sw = c ? sw1 : sw0;
      short8 af[2], bf[4];
#pragma unroll
      for (int mt = 0; mt < 2; ++mt)
        af[mt] = *(const short8*)&As[cur][(wq * 32 + mt * 16 + l15) * 64 + sw];
#pragma unroll
      for (int nt = 0; nt < 4; ++nt)
        bf[nt] = *(const short8*)&Bs[cur][(nt * 16 + l15) * 64 + sw];
#pragma unroll
      for (int mt = 0; mt < 2; ++mt)
#pragma unroll
        for (int nt = 0; nt < 4; ++nt)
          acc[mt][nt] = MFMA(af[mt], bf[nt], acc[mt][nt]);
    }
    if (ek + 64 < EMB) {
#pragma unroll
      for (int i = 0; i < 4; ++i) {
        int slot = i * 256 + t, row = slot >> 3, ch = slot & 7;
        *(short8*)&As[nxt][row * 64 + ((ch ^ (row & 7)) * 8)] = ar[i];
      }
#pragma unroll
      for (int i = 0; i < 2; ++i) {
        int slot = i * 256 + t, row = slot >> 3, ch = slot & 7;
        *(short8*)&Bs[nxt][row * 64 + ((ch ^ (row & 7)) * 8)] = br[i];
      }
    }
    __syncthreads();
  }

  float bn[4];
#pragma unroll
  for (int nt = 0; nt < 4; ++nt) bn[nt] = bo[j0 + nt * 16 + l15];
#pragma unroll
  for (int mt = 0; mt < 2; ++mt)
#pragma unroll
    for (int nt = 0; nt < 4; ++nt)
#pragma unroll
      for (int r = 0; r < 4; ++r)
        C[(size_t)(r0 + wq * 32 + mt * 16 + quad * 4 + r) * EMB + j0 +
          nt * 16 + l15] = acc[mt][nt][r] + bn[nt];
}

// ---------------------------------------------------------------------------
extern "C" void kernel_launch(void* const* d_in, const int* in_sizes, int n_in,
                              void* d_out, int out_size, void* d_ws,
                              size_t ws_size, hipStream_t stream) {
  const float* values = (const float*)d_in[0];
  const float* keys   = (const float*)d_in[1];
  const float* query  = (const float*)d_in[2];
  const int*   mask   = (const int*)d_in[3];
  const float* Wv     = (const float*)d_in[4];
  const float* Wk     = (const float*)d_in[5];
  const float* Wq     = (const float*)d_in[6];
  const float* Wo     = (const float*)d_in[7];
  const float* bo     = (const float*)d_in[8];
  float* out = (float*)d_out;

  short* ws = (short*)d_ws;
  const size_t tsz = (size_t)NB * NHEADS * LSEQ * HD;  // 4 Mi shorts
  short* Qb  = ws;
  short* Kb  = Qb + tsz;
  short* Vt  = Kb + tsz;
  short* AOb = Vt + tsz;

  dim3 blk(256);
  proj_mfma<<<dim3(LSEQ / 64, NB * NHEADS, 3), blk, 0, stream>>>(
      query, keys, values, Wq, Wk, Wv, mask, Qb, Kb, Vt);
  attn_kernel<<<dim3(256), dim3(512), 0, stream>>>(Qb, Kb, Vt, mask, AOb);
  outproj_mfma<<<dim3(512), blk, 0, stream>>>(AOb, Wo, bo, out);
}

// Round 7
// 197.819 us; speedup vs baseline: 1.1035x; 1.1035x over previous
//
#include <hip/hip_runtime.h>
#include <hip/hip_bf16.h>
#include <cstdint>

// MultiHeadSelfAttention N=2,L=2048,E=1024,H=16,D=64.
// Round 11: attn q-reuse x2 (r6-validated: LDS conflicts exactly halved)
// with register pressure fixed: ONE S accumulator sequenced a-then-b
// (K tile in 8 regs once), launch_bounds(512) w/o min-waves -> no spill
// (r6's 128-cap spill = +10MB scratch writes was the regression).
// Merge buffer aliases K/V LDS (64KB total). Non-attn restored to r1-era
// measured-best: conv converts weights once (Wo bf16, Wq*QSCALE), proj &
// outproj read bf16 weights (no f32 conversion on critical paths).
// Mask-at-source from raw ints (r4-proven); nmask computed in attn.

#define NB 2
#define LSEQ 2048
#define EMB 1024
#define NHEADS 16
#define HD 64

// (1/sqrt(1024)) * log2(e): folded into Wq bf16 conversion; P = exp2(S)
#define QSCALE 0.045084220027780106f

using short8 = __attribute__((ext_vector_type(8))) short;
using short4v = __attribute__((ext_vector_type(4))) short;
using f32x4 = __attribute__((ext_vector_type(4))) float;
using f32x16 = __attribute__((ext_vector_type(16))) float;
using uint2v = __attribute__((ext_vector_type(2))) unsigned int;

__device__ inline short bf16of(float f) {
  union { __hip_bfloat16 b; short s; } u;
  u.b = __float2bfloat16(f);
  return u.s;
}

__device__ inline short4v pack4bf(float a, float b, float c, float d) {
  union { __hip_bfloat162 v[2]; short4v s; } u;
  u.v[0] = __float22bfloat162_rn(make_float2(a, b));
  u.v[1] = __float22bfloat162_rn(make_float2(c, d));
  return u.s;
}

__device__ inline short8 pack8bf(float4 a, float4 b) {
  union { short4v q[2]; short8 o; } u;
  u.q[0] = pack4bf(a.x, a.y, a.z, a.w);
  u.q[1] = pack4bf(b.x, b.y, b.z, b.w);
  return u.o;
}

__device__ inline unsigned pk2(float lo, float hi) {
  union { __hip_bfloat162 v; unsigned u; } x;
  x.v = __float22bfloat162_rn(make_float2(lo, hi));
  return x.u;
}

// v_permlane32_swap_b32: a' = {a.lo, b.lo}, b' = {a.hi, b.hi}
__device__ inline void plswap(unsigned& a, unsigned& b) {
#if __has_builtin(__builtin_amdgcn_permlane32_swap)
  uint2v r = __builtin_amdgcn_permlane32_swap(a, b, false, false);
  a = r[0];
  b = r[1];
#else
  asm volatile("v_permlane32_swap_b32 %0, %1" : "+v"(a), "+v"(b));
#endif
}

__device__ inline float fexp2(float x) {
#if __has_builtin(__builtin_amdgcn_exp2f)
  return __builtin_amdgcn_exp2f(x);
#else
  return exp2f(x);
#endif
}

#define MFMA(A, B, C) __builtin_amdgcn_mfma_f32_16x16x32_bf16((A), (B), (C), 0, 0, 0)
#define MFMA32(A, B, C) __builtin_amdgcn_mfma_f32_32x32x16_bf16((A), (B), (C), 0, 0, 0)

// ---------------------------------------------------------------------------
// Weight conversion only: Wo->bf16 (grid-wide), Wq(*QSCALE)/Wk/Wv->bf16
// (blocks 0-2). Mask is consumed raw by proj/attn.
__global__ __launch_bounds__(256) void conv_kernel(
    const float* __restrict__ Wq, const float* __restrict__ Wk,
    const float* __restrict__ Wv, const float* __restrict__ Wo,
    short* __restrict__ Wqb, short* __restrict__ Wkb,
    short* __restrict__ Wvb, short* __restrict__ Wob) {
  const int b = blockIdx.x, t = threadIdx.x;
  {
    int i = (b * 256 + t) * 4;  // 1024 blocks * 1024 = 1Mi elements of Wo
    float4 v = *(const float4*)&Wo[i];
    *(short4v*)&Wob[i] = pack4bf(v.x, v.y, v.z, v.w);
  }
  if (b < 3) {
    const float* src = (b == 0) ? Wq : (b == 1) ? Wk : Wv;
    short* dst = (b == 0) ? Wqb : (b == 1) ? Wkb : Wvb;
    const float sc = (b == 0) ? QSCALE : 1.0f;
#pragma unroll
    for (int i = 0; i < 4; ++i) {
      int j = t * 16 + i * 4;  // 256*16 = 4096
      float4 v = *(const float4*)&src[j];
      *(short4v*)&dst[j] = pack4bf(v.x * sc, v.y * sc, v.z * sc, v.w * sc);
    }
  }
}

// ---------------------------------------------------------------------------
// LDS-free MFMA projections, bf16 weights (pre-converted; Wqb pre-scaled).
// Block = 4 waves, 64 l-rows, one (n,h,z). z==1 (K): masked rows zeroed
// (-> S column exactly 0 -> P exactly 1). z==2 (V): masked V^T cols zeroed.
__global__ __launch_bounds__(256) void proj_mfma(
    const float* __restrict__ xq, const float* __restrict__ xk,
    const float* __restrict__ xv, const short* __restrict__ Wqb,
    const short* __restrict__ Wkb, const short* __restrict__ Wvb,
    const int* __restrict__ mask, short* __restrict__ Qb,
    short* __restrict__ Kb, short* __restrict__ Vt) {
  const int t = threadIdx.x;
  const int wq = t >> 6, lane = t & 63;
  const int quad = lane >> 4, l15 = lane & 15;
  const int z = blockIdx.z, nh = blockIdx.y;
  const int n = nh >> 4, h = nh & 15;
  const int l0 = blockIdx.x * 64;
  const float* x = (z == 0) ? xq : (z == 1) ? xk : xv;
  const short* W = (z == 0) ? Wqb : (z == 1) ? Wkb : Wvb;
  const int lrow = l0 + wq * 16 + l15;  // this lane's l (n-index for z<2)

  // x fragment: 8 f32 -> bf16, k = e chunk c*32+quad*8
  short8 xf[2];
  const float* xr = x + ((size_t)n * LSEQ + lrow) * EMB + h * HD;
#pragma unroll
  for (int c = 0; c < 2; ++c) {
    float4 a = *(const float4*)(xr + c * 32 + quad * 8);
    float4 b = *(const float4*)(xr + c * 32 + quad * 8 + 4);
    xf[c] = pack8bf(a, b);
  }
  // W fragments: row (mt*16+l15) of W[d][e] (A for z<2; B=W^T for z==2)
  short8 wf[4][2];
#pragma unroll
  for (int mt = 0; mt < 4; ++mt)
#pragma unroll
    for (int c = 0; c < 2; ++c)
      wf[mt][c] = *(const short8*)(W + (mt * 16 + l15) * HD + c * 32 + quad * 8);

  f32x4 acc[4];
#pragma unroll
  for (int a = 0; a < 4; ++a) acc[a] = (f32x4){0.f, 0.f, 0.f, 0.f};

  if (z < 2) {
#pragma unroll
    for (int c = 0; c < 2; ++c)
#pragma unroll
      for (int mt = 0; mt < 4; ++mt) acc[mt] = MFMA(wf[mt][c], xf[c], acc[mt]);
    // K: zero masked rows at the source (Q: QSCALE already in Wqb)
    const float mk =
        (z == 1) ? (mask[n * LSEQ + lrow] ? 1.0f : 0.0f) : 1.0f;
    short* ob = ((z == 0) ? Qb : Kb) + ((size_t)nh * LSEQ + lrow) * HD;
#pragma unroll
    for (int mt = 0; mt < 4; ++mt)
      *(short4v*)&ob[mt * 16 + quad * 4] =
          pack4bf(acc[mt][0] * mk, acc[mt][1] * mk, acc[mt][2] * mk,
                  acc[mt][3] * mk);
  } else {
#pragma unroll
    for (int c = 0; c < 2; ++c)
#pragma unroll
      for (int nt = 0; nt < 4; ++nt) acc[nt] = MFMA(xf[c], wf[nt][c], acc[nt]);
    // C rows = l = l0 + wq*16 + quad*4 + r ; cols = d = nt*16+l15
    const int4 mi = *(const int4*)(mask + n * LSEQ + l0 + wq * 16 + quad * 4);
    f32x4 mv;
    mv[0] = mi.x ? 1.f : 0.f;
    mv[1] = mi.y ? 1.f : 0.f;
    mv[2] = mi.z ? 1.f : 0.f;
    mv[3] = mi.w ? 1.f : 0.f;
#pragma unroll
    for (int nt = 0; nt < 4; ++nt)
      *(short4v*)&Vt[((size_t)nh * HD + nt * 16 + l15) * LSEQ + l0 + wq * 16 +
                     quad * 4] =
          pack4bf(acc[nt][0] * mv[0], acc[nt][1] * mv[1], acc[nt][2] * mv[2],
                  acc[nt][3] * mv[3]);
  }
}

// ---------------------------------------------------------------------------
// Flash attention, 32x32 MFMA, q-reuse x2 + split-K, register-sequenced.
// Block = 512 threads = 8 waves: qg = wv&3 (owns 64 q as subtiles a/b),
// kh = wv>>2 (k half, 16 tiles). Grid 256 XCD-grouped -> 1 block/CU,
// 2 waves/SIMD. Per iteration: K tile -> 8 regs ONCE; QK_a -> SM_a ->
// QK_b (S reused; paa holds P_a) -> SM_b -> PV a+b with shared vf reads.
// LDS reads per q HALVED vs r9 (r10-verified: conflicts exactly 2^21).
// launch_bounds(512) without min-waves: ~210 VGPR, NO spill (r10 lesson:
// the (512,2) 128-cap caused +10MB scratch traffic).
// Masked K rows / V cols zero at source -> masked P == 1; l -= nmask.
// Split-K merge: 2 LDS rounds through buffer ALIASED onto K/V LDS
// (barrier-protected); kh==0 waves write output.
__global__ __launch_bounds__(512) void attn_kernel(
    const short* __restrict__ Qg,   // [nh][L][64] bf16 (Wq pre-scaled)
    const short* __restrict__ Kg,   // [nh][L][64] bf16 (masked rows zero)
    const short* __restrict__ Vtg,  // [nh][64][L] bf16 (masked cols zero)
    const int* __restrict__ mask,   // [N][L]
    short* __restrict__ AO)         // [N*L][E] bf16
{
  // [kv][kh][buf][4096] = 64KB; merge buffer aliases this after the loop.
  __shared__ __align__(16) short smem[2][2][2][4096];

  const int t = threadIdx.x;
  const int wv = t >> 6, lane = t & 63;
  const int l31 = lane & 31, hi = lane >> 5;
  const int qg = wv & 3, kh = wv >> 2;

  // XCD-grouped: 256 blocks, 32/XCD; nh = xcd*4 + (idx>>3), q0 = (idx&7)*256
  const int raw = blockIdx.x;
  const int xcd = raw & 7, idx = raw >> 3;
  const int nh = (xcd << 2) | (idx >> 3);
  const int q0 = (idx & 7) * 256;
  const int n = nh >> 4, h = nh & 15;

  // nmask: count of masked (==0) keys for this n (per-wave redundant)
  float nm = 0.f;
  {
    const int* mp = mask + n * LSEQ + lane * 32;
#pragma unroll
    for (int i = 0; i < 8; ++i) {
      int4 m = *(const int4*)(mp + i * 4);
      nm += (float)((m.x == 0) + (m.y == 0) + (m.z == 0) + (m.w == 0));
    }
#pragma unroll
    for (int o = 1; o < 64; o <<= 1) nm += __shfl_xor(nm, o);
  }

  // Q B-fragments for subtiles a (q0+qg*64+l31) and b (+32)
  short8 qfa[4], qfb[4];
  {
    const short* qra =
        Qg + ((size_t)nh * LSEQ + q0 + qg * 64 + l31) * HD + hi * 8;
    const short* qrb = qra + 32 * HD;
#pragma unroll
    for (int s = 0; s < 4; ++s) {
      qfa[s] = *(const short8*)(qra + s * 16);
      qfb[s] = *(const short8*)(qrb + s * 16);
    }
  }

  const short* kbase = Kg + ((size_t)nh * LSEQ + kh * (LSEQ / 2)) * HD;
  const short* vbase = Vtg + (size_t)nh * HD * LSEQ + kh * (LSEQ / 2);

  // staging: per half, its 256 threads cover 512 16B slots (rows ts>>3, +32)
  const int ts = t & 255;
  const int r0s = ts >> 3, cs = ts & 7, r1s = r0s + 32;
  const int ld0 = r0s * 64 + ((cs ^ (r0s & 7)) * 8);
  const int ld1 = r1s * 64 + ((cs ^ (r1s & 7)) * 8);

  // prologue: stage this half's tiles 0 and 1
#pragma unroll
  for (int pt = 0; pt < 2; ++pt) {
    const short* kb = kbase + (size_t)pt * 64 * HD;
    const short* vb = vbase + pt * 64;
    short8 k0 = *(const short8*)(kb + (size_t)r0s * HD + cs * 8);
    short8 k1 = *(const short8*)(kb + (size_t)r1s * HD + cs * 8);
    short8 v0 = *(const short8*)(vb + (size_t)r0s * LSEQ + cs * 8);
    short8 v1 = *(const short8*)(vb + (size_t)r1s * LSEQ + cs * 8);
    *(short8*)&smem[0][kh][pt][ld0] = k0;
    *(short8*)&smem[0][kh][pt][ld1] = k1;
    *(short8*)&smem[1][kh][pt][ld0] = v0;
    *(short8*)&smem[1][kh][pt][ld1] = v1;
  }
  __syncthreads();

  f32x16 Oa[2], Ob[2];
#pragma unroll
  for (int nt = 0; nt < 2; ++nt)
#pragma unroll
    for (int r = 0; r < 16; ++r) {
      Oa[nt][r] = 0.f;
      Ob[nt][r] = 0.f;
    }
  float lsa[4] = {0.f, 0.f, 0.f, 0.f};
  float lsb[4] = {0.f, 0.f, 0.f, 0.f};

#pragma unroll 1
  for (int it = 0; it < 16; ++it) {
    const int cur = it & 1;
    const bool haveLd = it < 14;
    short8 kr0, kr1, vr0, vr1;
    if (haveLd) {
      const short* kb = kbase + (size_t)(it + 2) * 64 * HD;
      const short* vb = vbase + (it + 2) * 64;
      kr0 = *(const short8*)(kb + (size_t)r0s * HD + cs * 8);
      kr1 = *(const short8*)(kb + (size_t)r1s * HD + cs * 8);
      vr0 = *(const short8*)(vb + (size_t)r0s * LSEQ + cs * 8);
      vr1 = *(const short8*)(vb + (size_t)r1s * LSEQ + cs * 8);
    }
    const short* ksb = &smem[0][kh][cur][0];
    const short* vsb = &smem[1][kh][cur][0];

    // ---- K tile into registers ONCE (8 b128 reads, feeds both subtiles)
    short8 kreg[8];
#pragma unroll
    for (int g = 0; g < 2; ++g) {
      const int row = g * 32 + l31;
      const int rb = row * 64, sx = row & 7;
#pragma unroll
      for (int s = 0; s < 4; ++s)
        kreg[g * 4 + s] = *(const short8*)(ksb + rb + (((s * 2 + hi) ^ sx) * 8));
    }

    // ---- QK_a
    f32x16 S[2];
#pragma unroll
    for (int g = 0; g < 2; ++g)
#pragma unroll
      for (int r = 0; r < 16; ++r) S[g][r] = 0.f;
    __builtin_amdgcn_s_setprio(1);
#pragma unroll
    for (int g = 0; g < 2; ++g)
#pragma unroll
      for (int s = 0; s < 4; ++s) S[g] = MFMA32(kreg[g * 4 + s], qfa[s], S[g]);
    __builtin_amdgcn_s_setprio(0);

    // ---- SM_a: P = exp2(S); row-sum; repack -> paa (frees S)
    short8 paa[4];
#pragma unroll
    for (int g = 0; g < 2; ++g) {
#pragma unroll
      for (int r = 0; r < 16; ++r) {
        float e = fexp2(S[g][r]);
        S[g][r] = e;
        lsa[r & 3] += e;
      }
#pragma unroll
      for (int hf = 0; hf < 2; ++hf) {
        unsigned w0 = pk2(S[g][hf * 8 + 0], S[g][hf * 8 + 1]);
        unsigned w2 = pk2(S[g][hf * 8 + 4], S[g][hf * 8 + 5]);
        plswap(w0, w2);
        unsigned w1 = pk2(S[g][hf * 8 + 2], S[g][hf * 8 + 3]);
        unsigned w3 = pk2(S[g][hf * 8 + 6], S[g][hf * 8 + 7]);
        plswap(w1, w3);
        union { unsigned u[4]; short8 s; } uo;
        uo.u[0] = w0;
        uo.u[1] = w1;
        uo.u[2] = w2;
        uo.u[3] = w3;
        paa[g * 2 + hf] = uo.s;
      }
    }

    // ---- QK_b (S reused; kreg still live)
#pragma unroll
    for (int g = 0; g < 2; ++g)
#pragma unroll
      for (int r = 0; r < 16; ++r) S[g][r] = 0.f;
    __builtin_amdgcn_s_setprio(1);
#pragma unroll
    for (int g = 0; g < 2; ++g)
#pragma unroll
      for (int s = 0; s < 4; ++s) S[g] = MFMA32(kreg[g * 4 + s], qfb[s], S[g]);
    __builtin_amdgcn_s_setprio(0);

    // ---- V fragments (shared by both subtiles); overlap SM_b below
    short8 vf[8];
#pragma unroll
    for (int s = 0; s < 4; ++s)
#pragma unroll
      for (int nt = 0; nt < 2; ++nt) {
        const int row = nt * 32 + l31;
        vf[s * 2 + nt] = *(const short8*)(vsb + row * 64 +
                                          (((s * 2 + hi) ^ (row & 7)) * 8));
      }

    // ---- SM_b
    short8 pab[4];
#pragma unroll
    for (int g = 0; g < 2; ++g) {
#pragma unroll
      for (int r = 0; r < 16; ++r) {
        float e = fexp2(S[g][r]);
        S[g][r] = e;
        lsb[r & 3] += e;
      }
#pragma unroll
      for (int hf = 0; hf < 2; ++hf) {
        unsigned w0 = pk2(S[g][hf * 8 + 0], S[g][hf * 8 + 1]);
        unsigned w2 = pk2(S[g][hf * 8 + 4], S[g][hf * 8 + 5]);
        plswap(w0, w2);
        unsigned w1 = pk2(S[g][hf * 8 + 2], S[g][hf * 8 + 3]);
        unsigned w3 = pk2(S[g][hf * 8 + 6], S[g][hf * 8 + 7]);
        plswap(w1, w3);
        union { unsigned u[4]; short8 s; } uo;
        uo.u[0] = w0;
        uo.u[1] = w1;
        uo.u[2] = w2;
        uo.u[3] = w3;
        pab[g * 2 + hf] = uo.s;
      }
    }

    // ---- PV both subtiles; each vf feeds 2 MFMAs
    __builtin_amdgcn_s_setprio(1);
#pragma unroll
    for (int s = 0; s < 4; ++s) {
      Oa[0] = MFMA32(paa[s], vf[2 * s], Oa[0]);
      Oa[1] = MFMA32(paa[s], vf[2 * s + 1], Oa[1]);
      Ob[0] = MFMA32(pab[s], vf[2 * s], Ob[0]);
      Ob[1] = MFMA32(pab[s], vf[2 * s + 1], Ob[1]);
    }
    __builtin_amdgcn_s_setprio(0);

    // ---- recycle buffer cur with tile it+2
    if (haveLd) {
      __syncthreads();  // all waves done reading buf cur
      *(short8*)&smem[0][kh][cur][ld0] = kr0;
      *(short8*)&smem[0][kh][cur][ld1] = kr1;
      *(short8*)&smem[1][kh][cur][ld0] = vr0;
      *(short8*)&smem[1][kh][cur][ld1] = vr1;
      __syncthreads();
    }
  }

  // ---- split-K merge through LDS (aliases K/V buffers; barrier first)
  __syncthreads();
  float la = (lsa[0] + lsa[1]) + (lsa[2] + lsa[3]);
  la += __shfl_xor(la, 32);
  float lb = (lsb[0] + lsb[1]) + (lsb[2] + lsb[3]);
  lb += __shfl_xor(lb, 32);

  float* xb = (float*)smem + (size_t)(qg * 64 + lane) * 36;  // 36.9KB < 64KB
  // round A
  if (kh == 1) {
#pragma unroll
    for (int nt = 0; nt < 2; ++nt)
#pragma unroll
      for (int c = 0; c < 4; ++c) {
        f32x4 v;
#pragma unroll
        for (int j = 0; j < 4; ++j) v[j] = Oa[nt][c * 4 + j];
        *(f32x4*)(xb + (nt * 4 + c) * 4) = v;
      }
    xb[32] = la;
  }
  __syncthreads();
  if (kh == 0) {
#pragma unroll
    for (int nt = 0; nt < 2; ++nt)
#pragma unroll
      for (int c = 0; c < 4; ++c) {
        f32x4 p = *(const f32x4*)(xb + (nt * 4 + c) * 4);
#pragma unroll
        for (int j = 0; j < 4; ++j) Oa[nt][c * 4 + j] += p[j];
      }
    la = la + xb[32] - nm;  // masked keys contributed exp2(0)=1 each
  }
  __syncthreads();
  // round B
  if (kh == 1) {
#pragma unroll
    for (int nt = 0; nt < 2; ++nt)
#pragma unroll
      for (int c = 0; c < 4; ++c) {
        f32x4 v;
#pragma unroll
        for (int j = 0; j < 4; ++j) v[j] = Ob[nt][c * 4 + j];
        *(f32x4*)(xb + (nt * 4 + c) * 4) = v;
      }
    xb[32] = lb;
  }
  __syncthreads();
  if (kh == 0) {
#pragma unroll
    for (int nt = 0; nt < 2; ++nt)
#pragma unroll
      for (int c = 0; c < 4; ++c) {
        f32x4 p = *(const f32x4*)(xb + (nt * 4 + c) * 4);
#pragma unroll
        for (int j = 0; j < 4; ++j) Ob[nt][c * 4 + j] += p[j];
      }
    lb = lb + xb[32] - nm;

    // ---- epilogue: O/l -> bf16 AO[n*L + q][h*64 + dv]
    const float linva = 1.0f / la;
    const float linvb = 1.0f / lb;
    short* ob = AO + ((size_t)n * LSEQ + q0 + qg * 64) * EMB + h * HD;
#pragma unroll
    for (int r = 0; r < 16; ++r) {
      const int qr = (r & 3) + 8 * (r >> 2) + 4 * hi;
      float lia = __int_as_float(
          __builtin_amdgcn_ds_bpermute(qr << 2, __float_as_int(linva)));
      float lib = __int_as_float(
          __builtin_amdgcn_ds_bpermute(qr << 2, __float_as_int(linvb)));
      ob[(size_t)qr * EMB + l31] = bf16of(Oa[0][r] * lia);
      ob[(size_t)qr * EMB + 32 + l31] = bf16of(Oa[1][r] * lia);
      ob[(size_t)(qr + 32) * EMB + l31] = bf16of(Ob[0][r] * lib);
      ob[(size_t)(qr + 32) * EMB + 32 + l31] = bf16of(Ob[1][r] * lib);
    }
  }
}

// ---------------------------------------------------------------------------
// Out-projection: C[r][j] = sum_e A[r][e]*Wo[j][e] + bo[j], bf16 Wob
// (pre-converted by conv -- no f32 conversion in the inner loop).
// 128x64 tile/block, grid 512, XCD-grouped by r-block. XOR-swizzled LDS,
// double-buffered, register prefetch.
__global__ __launch_bounds__(256, 2) void outproj_mfma(
    const short* __restrict__ A, const short* __restrict__ W,
    const float* __restrict__ bo, float* __restrict__ C) {
  __shared__ __align__(16) short As[2][128 * 64];
  __shared__ __align__(16) short Bs[2][64 * 64];
  const int t = threadIdx.x;
  const int wq = t >> 6, lane = t & 63;
  const int quad = lane >> 4, l15 = lane & 15;
  // XCD-grouped: 512 blocks, 64/XCD; ry = xcd*4 + (idx>>4), jx = idx&15.
  const int raw = blockIdx.x;
  const int xcd = raw & 7, idx = raw >> 3;
  const int ry = (xcd << 2) | (idx >> 4);
  const int j0 = (idx & 15) * 64, r0 = ry * 128;

  f32x4 acc[2][4];
#pragma unroll
  for (int a = 0; a < 2; ++a)
#pragma unroll
    for (int b = 0; b < 4; ++b) acc[a][b] = (f32x4){0.f, 0.f, 0.f, 0.f};

  // A: 1024 slots (row = slot>>3, ch = slot&7); B: 512 slots.
  short8 ar[4], br[2];
#pragma unroll
  for (int i = 0; i < 4; ++i) {
    int slot = i * 256 + t, row = slot >> 3, ch = slot & 7;
    ar[i] = *(const short8*)(A + (size_t)(r0 + row) * EMB + ch * 8);
  }
#pragma unroll
  for (int i = 0; i < 2; ++i) {
    int slot = i * 256 + t, row = slot >> 3, ch = slot & 7;
    br[i] = *(const short8*)(W + (size_t)(j0 + row) * EMB + ch * 8);
  }
#pragma unroll
  for (int i = 0; i < 4; ++i) {
    int slot = i * 256 + t, row = slot >> 3, ch = slot & 7;
    *(short8*)&As[0][row * 64 + ((ch ^ (row & 7)) * 8)] = ar[i];
  }
#pragma unroll
  for (int i = 0; i < 2; ++i) {
    int slot = i * 256 + t, row = slot >> 3, ch = slot & 7;
    *(short8*)&Bs[0][row * 64 + ((ch ^ (row & 7)) * 8)] = br[i];
  }
  __syncthreads();

  const int sw0 = ((0 * 4 + quad) ^ (l15 & 7)) * 8;
  const int sw1 = ((1 * 4 + quad) ^ (l15 & 7)) * 8;

  for (int ek = 0; ek < EMB; ek += 64) {
    const int cur = (ek >> 6) & 1, nxt = cur ^ 1;
    if (ek + 64 < EMB) {
#pragma unroll
      for (int i = 0; i < 4; ++i) {
        int slot = i * 256 + t, row = slot >> 3, ch = slot & 7;
        ar[i] = *(const short8*)(A + (size_t)(r0 + row) * EMB + ek + 64 + ch * 8);
      }
#pragma unroll
      for (int i = 0; i < 2; ++i) {
        int slot = i * 256 + t, row = slot >> 3, ch = slot & 7;
        br[i] = *(const short8*)(W + (size_t)(j0 + row) * EMB + ek + 64 + ch * 8);
      }
    }
#pragma unroll
    for (int c = 0; c < 2; ++c) {
      const int sw = c ? sw1 : sw0;
      short8 af[2], bf[4];
#pragma unroll
      for (int mt = 0; mt < 2; ++mt)
        af[mt] = *(const short8*)&As[cur][(wq * 32 + mt * 16 + l15) * 64 + sw];
#pragma unroll
      for (int nt = 0; nt < 4; ++nt)
        bf[nt] = *(const short8*)&Bs[cur][(nt * 16 + l15) * 64 + sw];
#pragma unroll
      for (int mt = 0; mt < 2; ++mt)
#pragma unroll
        for (int nt = 0; nt < 4; ++nt)
          acc[mt][nt] = MFMA(af[mt], bf[nt], acc[mt][nt]);
    }
    if (ek + 64 < EMB) {
#pragma unroll
      for (int i = 0; i < 4; ++i) {
        int slot = i * 256 + t, row = slot >> 3, ch = slot & 7;
        *(short8*)&As[nxt][row * 64 + ((ch ^ (row & 7)) * 8)] = ar[i];
      }
#pragma unroll
      for (int i = 0; i < 2; ++i) {
        int slot = i * 256 + t, row = slot >> 3, ch = slot & 7;
        *(short8*)&Bs[nxt][row * 64 + ((ch ^ (row & 7)) * 8)] = br[i];
      }
    }
    __syncthreads();
  }

  float bn[4];
#pragma unroll
  for (int nt = 0; nt < 4; ++nt) bn[nt] = bo[j0 + nt * 16 + l15];
#pragma unroll
  for (int mt = 0; mt < 2; ++mt)
#pragma unroll
    for (int nt = 0; nt < 4; ++nt)
#pragma unroll
      for (int r = 0; r < 4; ++r)
        C[(size_t)(r0 + wq * 32 + mt * 16 + quad * 4 + r) * EMB + j0 +
          nt * 16 + l15] = acc[mt][nt][r] + bn[nt];
}

// ---------------------------------------------------------------------------
extern "C" void kernel_launch(void* const* d_in, const int* in_sizes, int n_in,
                              void* d_out, int out_size, void* d_ws,
                              size_t ws_size, hipStream_t stream) {
  const float* values = (const float*)d_in[0];
  const float* keys   = (const float*)d_in[1];
  const float* query  = (const float*)d_in[2];
  const int*   mask   = (const int*)d_in[3];
  const float* Wv     = (const float*)d_in[4];
  const float* Wk     = (const float*)d_in[5];
  const float* Wq     = (const float*)d_in[6];
  const float* Wo     = (const float*)d_in[7];
  const float* bo     = (const float*)d_in[8];
  float* out = (float*)d_out;

  short* ws = (short*)d_ws;
  const size_t tsz = (size_t)NB * NHEADS * LSEQ * HD;  // 4 Mi shorts
  short* Qb  = ws;
  short* Kb  = Qb + tsz;
  short* Vt  = Kb + tsz;
  short* AOb = Vt + tsz;
  short* Wob = AOb + tsz;                // 1 Mi shorts
  short* Wqb = Wob + (size_t)EMB * EMB;  // 4096 each
  short* Wkb = Wqb + HD * HD;
  short* Wvb = Wkb + HD * HD;

  dim3 blk(256);
  conv_kernel<<<dim3(1024), blk, 0, stream>>>(Wq, Wk, Wv, Wo, Wqb, Wkb, Wvb,
                                              Wob);
  proj_mfma<<<dim3(LSEQ / 64, NB * NHEADS, 3), blk, 0, stream>>>(
      query, keys, values, Wqb, Wkb, Wvb, mask, Qb, Kb, Vt);
  attn_kernel<<<dim3(256), dim3(512), 0, stream>>>(Qb, Kb, Vt, mask, AOb);
  outproj_mfma<<<dim3(512), blk, 0, stream>>>(AOb, Wob, bo, out);
}

// Round 8
// 196.764 us; speedup vs baseline: 1.1094x; 1.0054x over previous
//
#include <hip/hip_runtime.h>
#include <hip/hip_bf16.h>
#include <cstdint>

// MultiHeadSelfAttention N=2,L=2048,E=1024,H=16,D=64.
// Round 12: single-variable A/B vs round 11 -- attn_kernel now carries
// amdgpu_waves_per_eu(2,2) (+ flat_work_group_size 512). r11 post-mortem:
// allocator's default for 512-thr blocks targets 4 waves/EU -> 128 VGPR ->
// ~9MB scratch spill (WRITE_SIZE 17.4 vs 8.2 ideal). The q-reuse x2 live
// set is ~210 VGPR; waves_per_eu(2,2) raises the budget to 256 -> no spill.
// Check: VGPR_Count ~200-256, WRITE_SIZE ~8.3MB. Everything else identical
// to round 11 (q-reuse x2 + split-K, LDS conflicts verified halved; conv +
// bf16-weight proj/outproj restored).

#define NB 2
#define LSEQ 2048
#define EMB 1024
#define NHEADS 16
#define HD 64

// (1/sqrt(1024)) * log2(e): folded into Wq bf16 conversion; P = exp2(S)
#define QSCALE 0.045084220027780106f

using short8 = __attribute__((ext_vector_type(8))) short;
using short4v = __attribute__((ext_vector_type(4))) short;
using f32x4 = __attribute__((ext_vector_type(4))) float;
using f32x16 = __attribute__((ext_vector_type(16))) float;
using uint2v = __attribute__((ext_vector_type(2))) unsigned int;

__device__ inline short bf16of(float f) {
  union { __hip_bfloat16 b; short s; } u;
  u.b = __float2bfloat16(f);
  return u.s;
}

__device__ inline short4v pack4bf(float a, float b, float c, float d) {
  union { __hip_bfloat162 v[2]; short4v s; } u;
  u.v[0] = __float22bfloat162_rn(make_float2(a, b));
  u.v[1] = __float22bfloat162_rn(make_float2(c, d));
  return u.s;
}

__device__ inline short8 pack8bf(float4 a, float4 b) {
  union { short4v q[2]; short8 o; } u;
  u.q[0] = pack4bf(a.x, a.y, a.z, a.w);
  u.q[1] = pack4bf(b.x, b.y, b.z, b.w);
  return u.o;
}

__device__ inline unsigned pk2(float lo, float hi) {
  union { __hip_bfloat162 v; unsigned u; } x;
  x.v = __float22bfloat162_rn(make_float2(lo, hi));
  return x.u;
}

// v_permlane32_swap_b32: a' = {a.lo, b.lo}, b' = {a.hi, b.hi}
__device__ inline void plswap(unsigned& a, unsigned& b) {
#if __has_builtin(__builtin_amdgcn_permlane32_swap)
  uint2v r = __builtin_amdgcn_permlane32_swap(a, b, false, false);
  a = r[0];
  b = r[1];
#else
  asm volatile("v_permlane32_swap_b32 %0, %1" : "+v"(a), "+v"(b));
#endif
}

__device__ inline float fexp2(float x) {
#if __has_builtin(__builtin_amdgcn_exp2f)
  return __builtin_amdgcn_exp2f(x);
#else
  return exp2f(x);
#endif
}

#define MFMA(A, B, C) __builtin_amdgcn_mfma_f32_16x16x32_bf16((A), (B), (C), 0, 0, 0)
#define MFMA32(A, B, C) __builtin_amdgcn_mfma_f32_32x32x16_bf16((A), (B), (C), 0, 0, 0)

// ---------------------------------------------------------------------------
// Weight conversion only: Wo->bf16 (grid-wide), Wq(*QSCALE)/Wk/Wv->bf16
// (blocks 0-2). Mask is consumed raw by proj/attn.
__global__ __launch_bounds__(256) void conv_kernel(
    const float* __restrict__ Wq, const float* __restrict__ Wk,
    const float* __restrict__ Wv, const float* __restrict__ Wo,
    short* __restrict__ Wqb, short* __restrict__ Wkb,
    short* __restrict__ Wvb, short* __restrict__ Wob) {
  const int b = blockIdx.x, t = threadIdx.x;
  {
    int i = (b * 256 + t) * 4;  // 1024 blocks * 1024 = 1Mi elements of Wo
    float4 v = *(const float4*)&Wo[i];
    *(short4v*)&Wob[i] = pack4bf(v.x, v.y, v.z, v.w);
  }
  if (b < 3) {
    const float* src = (b == 0) ? Wq : (b == 1) ? Wk : Wv;
    short* dst = (b == 0) ? Wqb : (b == 1) ? Wkb : Wvb;
    const float sc = (b == 0) ? QSCALE : 1.0f;
#pragma unroll
    for (int i = 0; i < 4; ++i) {
      int j = t * 16 + i * 4;  // 256*16 = 4096
      float4 v = *(const float4*)&src[j];
      *(short4v*)&dst[j] = pack4bf(v.x * sc, v.y * sc, v.z * sc, v.w * sc);
    }
  }
}

// ---------------------------------------------------------------------------
// LDS-free MFMA projections, bf16 weights (pre-converted; Wqb pre-scaled).
// Block = 4 waves, 64 l-rows, one (n,h,z). z==1 (K): masked rows zeroed
// (-> S column exactly 0 -> P exactly 1). z==2 (V): masked V^T cols zeroed.
__global__ __launch_bounds__(256) void proj_mfma(
    const float* __restrict__ xq, const float* __restrict__ xk,
    const float* __restrict__ xv, const short* __restrict__ Wqb,
    const short* __restrict__ Wkb, const short* __restrict__ Wvb,
    const int* __restrict__ mask, short* __restrict__ Qb,
    short* __restrict__ Kb, short* __restrict__ Vt) {
  const int t = threadIdx.x;
  const int wq = t >> 6, lane = t & 63;
  const int quad = lane >> 4, l15 = lane & 15;
  const int z = blockIdx.z, nh = blockIdx.y;
  const int n = nh >> 4, h = nh & 15;
  const int l0 = blockIdx.x * 64;
  const float* x = (z == 0) ? xq : (z == 1) ? xk : xv;
  const short* W = (z == 0) ? Wqb : (z == 1) ? Wkb : Wvb;
  const int lrow = l0 + wq * 16 + l15;  // this lane's l (n-index for z<2)

  // x fragment: 8 f32 -> bf16, k = e chunk c*32+quad*8
  short8 xf[2];
  const float* xr = x + ((size_t)n * LSEQ + lrow) * EMB + h * HD;
#pragma unroll
  for (int c = 0; c < 2; ++c) {
    float4 a = *(const float4*)(xr + c * 32 + quad * 8);
    float4 b = *(const float4*)(xr + c * 32 + quad * 8 + 4);
    xf[c] = pack8bf(a, b);
  }
  // W fragments: row (mt*16+l15) of W[d][e] (A for z<2; B=W^T for z==2)
  short8 wf[4][2];
#pragma unroll
  for (int mt = 0; mt < 4; ++mt)
#pragma unroll
    for (int c = 0; c < 2; ++c)
      wf[mt][c] = *(const short8*)(W + (mt * 16 + l15) * HD + c * 32 + quad * 8);

  f32x4 acc[4];
#pragma unroll
  for (int a = 0; a < 4; ++a) acc[a] = (f32x4){0.f, 0.f, 0.f, 0.f};

  if (z < 2) {
#pragma unroll
    for (int c = 0; c < 2; ++c)
#pragma unroll
      for (int mt = 0; mt < 4; ++mt) acc[mt] = MFMA(wf[mt][c], xf[c], acc[mt]);
    // K: zero masked rows at the source (Q: QSCALE already in Wqb)
    const float mk =
        (z == 1) ? (mask[n * LSEQ + lrow] ? 1.0f : 0.0f) : 1.0f;
    short* ob = ((z == 0) ? Qb : Kb) + ((size_t)nh * LSEQ + lrow) * HD;
#pragma unroll
    for (int mt = 0; mt < 4; ++mt)
      *(short4v*)&ob[mt * 16 + quad * 4] =
          pack4bf(acc[mt][0] * mk, acc[mt][1] * mk, acc[mt][2] * mk,
                  acc[mt][3] * mk);
  } else {
#pragma unroll
    for (int c = 0; c < 2; ++c)
#pragma unroll
      for (int nt = 0; nt < 4; ++nt) acc[nt] = MFMA(xf[c], wf[nt][c], acc[nt]);
    // C rows = l = l0 + wq*16 + quad*4 + r ; cols = d = nt*16+l15
    const int4 mi = *(const int4*)(mask + n * LSEQ + l0 + wq * 16 + quad * 4);
    f32x4 mv;
    mv[0] = mi.x ? 1.f : 0.f;
    mv[1] = mi.y ? 1.f : 0.f;
    mv[2] = mi.z ? 1.f : 0.f;
    mv[3] = mi.w ? 1.f : 0.f;
#pragma unroll
    for (int nt = 0; nt < 4; ++nt)
      *(short4v*)&Vt[((size_t)nh * HD + nt * 16 + l15) * LSEQ + l0 + wq * 16 +
                     quad * 4] =
          pack4bf(acc[nt][0] * mv[0], acc[nt][1] * mv[1], acc[nt][2] * mv[2],
                  acc[nt][3] * mv[3]);
  }
}

// ---------------------------------------------------------------------------
// Flash attention, 32x32 MFMA, q-reuse x2 + split-K, register-sequenced.
// Block = 512 threads = 8 waves: qg = wv&3 (owns 64 q as subtiles a/b),
// kh = wv>>2 (k half, 16 tiles). Grid 256 XCD-grouped -> 1 block/CU,
// 2 waves/SIMD. amdgpu_waves_per_eu(2,2): allocator budget 256 VGPR ->
// the ~210-reg live set fits with NO spill (r11: default 128 -> 9MB scratch).
// Per iteration: K tile -> 8 regs ONCE; QK_a -> SM_a -> QK_b (S reused) ->
// SM_b -> PV a+b with shared vf reads. LDS reads per q halved (verified).
// Masked K rows / V cols zero at source -> masked P == 1; l -= nmask.
// Split-K merge: 2 LDS rounds through buffer aliased onto K/V LDS.
__global__ __attribute__((amdgpu_flat_work_group_size(512, 512),
                          amdgpu_waves_per_eu(2, 2))) void attn_kernel(
    const short* __restrict__ Qg,   // [nh][L][64] bf16 (Wq pre-scaled)
    const short* __restrict__ Kg,   // [nh][L][64] bf16 (masked rows zero)
    const short* __restrict__ Vtg,  // [nh][64][L] bf16 (masked cols zero)
    const int* __restrict__ mask,   // [N][L]
    short* __restrict__ AO)         // [N*L][E] bf16
{
  // [kv][kh][buf][4096] = 64KB; merge buffer aliases this after the loop.
  __shared__ __align__(16) short smem[2][2][2][4096];

  const int t = threadIdx.x;
  const int wv = t >> 6, lane = t & 63;
  const int l31 = lane & 31, hi = lane >> 5;
  const int qg = wv & 3, kh = wv >> 2;

  // XCD-grouped: 256 blocks, 32/XCD; nh = xcd*4 + (idx>>3), q0 = (idx&7)*256
  const int raw = blockIdx.x;
  const int xcd = raw & 7, idx = raw >> 3;
  const int nh = (xcd << 2) | (idx >> 3);
  const int q0 = (idx & 7) * 256;
  const int n = nh >> 4, h = nh & 15;

  // nmask: count of masked (==0) keys for this n (per-wave redundant)
  float nm = 0.f;
  {
    const int* mp = mask + n * LSEQ + lane * 32;
#pragma unroll
    for (int i = 0; i < 8; ++i) {
      int4 m = *(const int4*)(mp + i * 4);
      nm += (float)((m.x == 0) + (m.y == 0) + (m.z == 0) + (m.w == 0));
    }
#pragma unroll
    for (int o = 1; o < 64; o <<= 1) nm += __shfl_xor(nm, o);
  }

  // Q B-fragments for subtiles a (q0+qg*64+l31) and b (+32)
  short8 qfa[4], qfb[4];
  {
    const short* qra =
        Qg + ((size_t)nh * LSEQ + q0 + qg * 64 + l31) * HD + hi * 8;
    const short* qrb = qra + 32 * HD;
#pragma unroll
    for (int s = 0; s < 4; ++s) {
      qfa[s] = *(const short8*)(qra + s * 16);
      qfb[s] = *(const short8*)(qrb + s * 16);
    }
  }

  const short* kbase = Kg + ((size_t)nh * LSEQ + kh * (LSEQ / 2)) * HD;
  const short* vbase = Vtg + (size_t)nh * HD * LSEQ + kh * (LSEQ / 2);

  // staging: per half, its 256 threads cover 512 16B slots (rows ts>>3, +32)
  const int ts = t & 255;
  const int r0s = ts >> 3, cs = ts & 7, r1s = r0s + 32;
  const int ld0 = r0s * 64 + ((cs ^ (r0s & 7)) * 8);
  const int ld1 = r1s * 64 + ((cs ^ (r1s & 7)) * 8);

  // prologue: stage this half's tiles 0 and 1
#pragma unroll
  for (int pt = 0; pt < 2; ++pt) {
    const short* kb = kbase + (size_t)pt * 64 * HD;
    const short* vb = vbase + pt * 64;
    short8 k0 = *(const short8*)(kb + (size_t)r0s * HD + cs * 8);
    short8 k1 = *(const short8*)(kb + (size_t)r1s * HD + cs * 8);
    short8 v0 = *(const short8*)(vb + (size_t)r0s * LSEQ + cs * 8);
    short8 v1 = *(const short8*)(vb + (size_t)r1s * LSEQ + cs * 8);
    *(short8*)&smem[0][kh][pt][ld0] = k0;
    *(short8*)&smem[0][kh][pt][ld1] = k1;
    *(short8*)&smem[1][kh][pt][ld0] = v0;
    *(short8*)&smem[1][kh][pt][ld1] = v1;
  }
  __syncthreads();

  f32x16 Oa[2], Ob[2];
#pragma unroll
  for (int nt = 0; nt < 2; ++nt)
#pragma unroll
    for (int r = 0; r < 16; ++r) {
      Oa[nt][r] = 0.f;
      Ob[nt][r] = 0.f;
    }
  float lsa[4] = {0.f, 0.f, 0.f, 0.f};
  float lsb[4] = {0.f, 0.f, 0.f, 0.f};

#pragma unroll 1
  for (int it = 0; it < 16; ++it) {
    const int cur = it & 1;
    const bool haveLd = it < 14;
    short8 kr0, kr1, vr0, vr1;
    if (haveLd) {
      const short* kb = kbase + (size_t)(it + 2) * 64 * HD;
      const short* vb = vbase + (it + 2) * 64;
      kr0 = *(const short8*)(kb + (size_t)r0s * HD + cs * 8);
      kr1 = *(const short8*)(kb + (size_t)r1s * HD + cs * 8);
      vr0 = *(const short8*)(vb + (size_t)r0s * LSEQ + cs * 8);
      vr1 = *(const short8*)(vb + (size_t)r1s * LSEQ + cs * 8);
    }
    const short* ksb = &smem[0][kh][cur][0];
    const short* vsb = &smem[1][kh][cur][0];

    // ---- K tile into registers ONCE (8 b128 reads, feeds both subtiles)
    short8 kreg[8];
#pragma unroll
    for (int g = 0; g < 2; ++g) {
      const int row = g * 32 + l31;
      const int rb = row * 64, sx = row & 7;
#pragma unroll
      for (int s = 0; s < 4; ++s)
        kreg[g * 4 + s] = *(const short8*)(ksb + rb + (((s * 2 + hi) ^ sx) * 8));
    }

    // ---- QK_a
    f32x16 S[2];
#pragma unroll
    for (int g = 0; g < 2; ++g)
#pragma unroll
      for (int r = 0; r < 16; ++r) S[g][r] = 0.f;
    __builtin_amdgcn_s_setprio(1);
#pragma unroll
    for (int g = 0; g < 2; ++g)
#pragma unroll
      for (int s = 0; s < 4; ++s) S[g] = MFMA32(kreg[g * 4 + s], qfa[s], S[g]);
    __builtin_amdgcn_s_setprio(0);

    // ---- SM_a: P = exp2(S); row-sum; repack -> paa (frees S)
    short8 paa[4];
#pragma unroll
    for (int g = 0; g < 2; ++g) {
#pragma unroll
      for (int r = 0; r < 16; ++r) {
        float e = fexp2(S[g][r]);
        S[g][r] = e;
        lsa[r & 3] += e;
      }
#pragma unroll
      for (int hf = 0; hf < 2; ++hf) {
        unsigned w0 = pk2(S[g][hf * 8 + 0], S[g][hf * 8 + 1]);
        unsigned w2 = pk2(S[g][hf * 8 + 4], S[g][hf * 8 + 5]);
        plswap(w0, w2);
        unsigned w1 = pk2(S[g][hf * 8 + 2], S[g][hf * 8 + 3]);
        unsigned w3 = pk2(S[g][hf * 8 + 6], S[g][hf * 8 + 7]);
        plswap(w1, w3);
        union { unsigned u[4]; short8 s; } uo;
        uo.u[0] = w0;
        uo.u[1] = w1;
        uo.u[2] = w2;
        uo.u[3] = w3;
        paa[g * 2 + hf] = uo.s;
      }
    }

    // ---- QK_b (S reused; kreg still live)
#pragma unroll
    for (int g = 0; g < 2; ++g)
#pragma unroll
      for (int r = 0; r < 16; ++r) S[g][r] = 0.f;
    __builtin_amdgcn_s_setprio(1);
#pragma unroll
    for (int g = 0; g < 2; ++g)
#pragma unroll
      for (int s = 0; s < 4; ++s) S[g] = MFMA32(kreg[g * 4 + s], qfb[s], S[g]);
    __builtin_amdgcn_s_setprio(0);

    // ---- V fragments (shared by both subtiles); overlap SM_b below
    short8 vf[8];
#pragma unroll
    for (int s = 0; s < 4; ++s)
#pragma unroll
      for (int nt = 0; nt < 2; ++nt) {
        const int row = nt * 32 + l31;
        vf[s * 2 + nt] = *(const short8*)(vsb + row * 64 +
                                          (((s * 2 + hi) ^ (row & 7)) * 8));
      }

    // ---- SM_b
    short8 pab[4];
#pragma unroll
    for (int g = 0; g < 2; ++g) {
#pragma unroll
      for (int r = 0; r < 16; ++r) {
        float e = fexp2(S[g][r]);
        S[g][r] = e;
        lsb[r & 3] += e;
      }
#pragma unroll
      for (int hf = 0; hf < 2; ++hf) {
        unsigned w0 = pk2(S[g][hf * 8 + 0], S[g][hf * 8 + 1]);
        unsigned w2 = pk2(S[g][hf * 8 + 4], S[g][hf * 8 + 5]);
        plswap(w0, w2);
        unsigned w1 = pk2(S[g][hf * 8 + 2], S[g][hf * 8 + 3]);
        unsigned w3 = pk2(S[g][hf * 8 + 6], S[g][hf * 8 + 7]);
        plswap(w1, w3);
        union { unsigned u[4]; short8 s; } uo;
        uo.u[0] = w0;
        uo.u[1] = w1;
        uo.u[2] = w2;
        uo.u[3] = w3;
        pab[g * 2 + hf] = uo.s;
      }
    }

    // ---- PV both subtiles; each vf feeds 2 MFMAs
    __builtin_amdgcn_s_setprio(1);
#pragma unroll
    for (int s = 0; s < 4; ++s) {
      Oa[0] = MFMA32(paa[s], vf[2 * s], Oa[0]);
      Oa[1] = MFMA32(paa[s], vf[2 * s + 1], Oa[1]);
      Ob[0] = MFMA32(pab[s], vf[2 * s], Ob[0]);
      Ob[1] = MFMA32(pab[s], vf[2 * s + 1], Ob[1]);
    }
    __builtin_amdgcn_s_setprio(0);

    // ---- recycle buffer cur with tile it+2
    if (haveLd) {
      __syncthreads();  // all waves done reading buf cur
      *(short8*)&smem[0][kh][cur][ld0] = kr0;
      *(short8*)&smem[0][kh][cur][ld1] = kr1;
      *(short8*)&smem[1][kh][cur][ld0] = vr0;
      *(short8*)&smem[1][kh][cur][ld1] = vr1;
      __syncthreads();
    }
  }

  // ---- split-K merge through LDS (aliases K/V buffers; barrier first)
  __syncthreads();
  float la = (lsa[0] + lsa[1]) + (lsa[2] + lsa[3]);
  la += __shfl_xor(la, 32);
  float lb = (lsb[0] + lsb[1]) + (lsb[2] + lsb[3]);
  lb += __shfl_xor(lb, 32);

  float* xb = (float*)smem + (size_t)(qg * 64 + lane) * 36;  // 36.9KB < 64KB
  // round A
  if (kh == 1) {
#pragma unroll
    for (int nt = 0; nt < 2; ++nt)
#pragma unroll
      for (int c = 0; c < 4; ++c) {
        f32x4 v;
#pragma unroll
        for (int j = 0; j < 4; ++j) v[j] = Oa[nt][c * 4 + j];
        *(f32x4*)(xb + (nt * 4 + c) * 4) = v;
      }
    xb[32] = la;
  }
  __syncthreads();
  if (kh == 0) {
#pragma unroll
    for (int nt = 0; nt < 2; ++nt)
#pragma unroll
      for (int c = 0; c < 4; ++c) {
        f32x4 p = *(const f32x4*)(xb + (nt * 4 + c) * 4);
#pragma unroll
        for (int j = 0; j < 4; ++j) Oa[nt][c * 4 + j] += p[j];
      }
    la = la + xb[32] - nm;  // masked keys contributed exp2(0)=1 each
  }
  __syncthreads();
  // round B
  if (kh == 1) {
#pragma unroll
    for (int nt = 0; nt < 2; ++nt)
#pragma unroll
      for (int c = 0; c < 4; ++c) {
        f32x4 v;
#pragma unroll
        for (int j = 0; j < 4; ++j) v[j] = Ob[nt][c * 4 + j];
        *(f32x4*)(xb + (nt * 4 + c) * 4) = v;
      }
    xb[32] = lb;
  }
  __syncthreads();
  if (kh == 0) {
#pragma unroll
    for (int nt = 0; nt < 2; ++nt)
#pragma unroll
      for (int c = 0; c < 4; ++c) {
        f32x4 p = *(const f32x4*)(xb + (nt * 4 + c) * 4);
#pragma unroll
        for (int j = 0; j < 4; ++j) Ob[nt][c * 4 + j] += p[j];
      }
    lb = lb + xb[32] - nm;

    // ---- epilogue: O/l -> bf16 AO[n*L + q][h*64 + dv]
    const float linva = 1.0f / la;
    const float linvb = 1.0f / lb;
    short* ob = AO + ((size_t)n * LSEQ + q0 + qg * 64) * EMB + h * HD;
#pragma unroll
    for (int r = 0; r < 16; ++r) {
      const int qr = (r & 3) + 8 * (r >> 2) + 4 * hi;
      float lia = __int_as_float(
          __builtin_amdgcn_ds_bpermute(qr << 2, __float_as_int(linva)));
      float lib = __int_as_float(
          __builtin_amdgcn_ds_bpermute(qr << 2, __float_as_int(linvb)));
      ob[(size_t)qr * EMB + l31] = bf16of(Oa[0][r] * lia);
      ob[(size_t)qr * EMB + 32 + l31] = bf16of(Oa[1][r] * lia);
      ob[(size_t)(qr + 32) * EMB + l31] = bf16of(Ob[0][r] * lib);
      ob[(size_t)(qr + 32) * EMB + 32 + l31] = bf16of(Ob[1][r] * lib);
    }
  }
}

// ---------------------------------------------------------------------------
// Out-projection: C[r][j] = sum_e A[r][e]*Wo[j][e] + bo[j], bf16 Wob
// (pre-converted by conv -- no f32 conversion in the inner loop).
// 128x64 tile/block, grid 512, XCD-grouped by r-block. XOR-swizzled LDS,
// double-buffered, register prefetch.
__global__ __launch_bounds__(256, 2) void outproj_mfma(
    const short* __restrict__ A, const short* __restrict__ W,
    const float* __restrict__ bo, float* __restrict__ C) {
  __shared__ __align__(16) short As[2][128 * 64];
  __shared__ __align__(16) short Bs[2][64 * 64];
  const int t = threadIdx.x;
  const int wq = t >> 6, lane = t & 63;
  const int quad = lane >> 4, l15 = lane & 15;
  // XCD-grouped: 512 blocks, 64/XCD; ry = xcd*4 + (idx>>4), jx = idx&15.
  const int raw = blockIdx.x;
  const int xcd = raw & 7, idx = raw >> 3;
  const int ry = (xcd << 2) | (idx >> 4);
  const int j0 = (idx & 15) * 64, r0 = ry * 128;

  f32x4 acc[2][4];
#pragma unroll
  for (int a = 0; a < 2; ++a)
#pragma unroll
    for (int b = 0; b < 4; ++b) acc[a][b] = (f32x4){0.f, 0.f, 0.f, 0.f};

  // A: 1024 slots (row = slot>>3, ch = slot&7); B: 512 slots.
  short8 ar[4], br[2];
#pragma unroll
  for (int i = 0; i < 4; ++i) {
    int slot = i * 256 + t, row = slot >> 3, ch = slot & 7;
    ar[i] = *(const short8*)(A + (size_t)(r0 + row) * EMB + ch * 8);
  }
#pragma unroll
  for (int i = 0; i < 2; ++i) {
    int slot = i * 256 + t, row = slot >> 3, ch = slot & 7;
    br[i] = *(const short8*)(W + (size_t)(j0 + row) * EMB + ch * 8);
  }
#pragma unroll
  for (int i = 0; i < 4; ++i) {
    int slot = i * 256 + t, row = slot >> 3, ch = slot & 7;
    *(short8*)&As[0][row * 64 + ((ch ^ (row & 7)) * 8)] = ar[i];
  }
#pragma unroll
  for (int i = 0; i < 2; ++i) {
    int slot = i * 256 + t, row = slot >> 3, ch = slot & 7;
    *(short8*)&Bs[0][row * 64 + ((ch ^ (row & 7)) * 8)] = br[i];
  }
  __syncthreads();

  const int sw0 = ((0 * 4 + quad) ^ (l15 & 7)) * 8;
  const int sw1 = ((1 * 4 + quad) ^ (l15 & 7)) * 8;

  for (int ek = 0; ek < EMB; ek += 64) {
    const int cur = (ek >> 6) & 1, nxt = cur ^ 1;
    if (ek + 64 < EMB) {
#pragma unroll
      for (int i = 0; i < 4; ++i) {
        int slot = i * 256 + t, row = slot >> 3, ch = slot & 7;
        ar[i] = *(const short8*)(A + (size_t)(r0 + row) * EMB + ek + 64 + ch * 8);
      }
#pragma unroll
      for (int i = 0; i < 2; ++i) {
        int slot = i * 256 + t, row = slot >> 3, ch = slot & 7;
        br[i] = *(const short8*)(W + (size_t)(j0 + row) * EMB + ek + 64 + ch * 8);
      }
    }
#pragma unroll
    for (int c = 0; c < 2; ++c) {
      const int sw = c ? sw1 : sw0;
      short8 af[2], bf[4];
#pragma unroll
      for (int mt = 0; mt < 2; ++mt)
        af[mt] = *(const short8*)&As[cur][(wq * 32 + mt * 16 + l15) * 64 + sw];
#pragma unroll
      for (int nt = 0; nt < 4; ++nt)
        bf[nt] = *(const short8*)&Bs[cur][(nt * 16 + l15) * 64 + sw];
#pragma unroll
      for (int mt = 0; mt < 2; ++mt)
#pragma unroll
        for (int nt = 0; nt < 4; ++nt)
          acc[mt][nt] = MFMA(af[mt], bf[nt], acc[mt][nt]);
    }
    if (ek + 64 < EMB) {
#pragma unroll
      for (int i = 0; i < 4; ++i) {
        int slot = i * 256 + t, row = slot >> 3, ch = slot & 7;
        *(short8*)&As[nxt][row * 64 + ((ch ^ (row & 7)) * 8)] = ar[i];
      }
#pragma unroll
      for (int i = 0; i < 2; ++i) {
        int slot = i * 256 + t, row = slot >> 3, ch = slot & 7;
        *(short8*)&Bs[nxt][row * 64 + ((ch ^ (row & 7)) * 8)] = br[i];
      }
    }
    __syncthreads();
  }

  float bn[4];
#pragma unroll
  for (int nt = 0; nt < 4; ++nt) bn[nt] = bo[j0 + nt * 16 + l15];
#pragma unroll
  for (int mt = 0; mt < 2; ++mt)
#pragma unroll
    for (int nt = 0; nt < 4; ++nt)
#pragma unroll
      for (int r = 0; r < 4; ++r)
        C[(size_t)(r0 + wq * 32 + mt * 16 + quad * 4 + r) * EMB + j0 +
          nt * 16 + l15] = acc[mt][nt][r] + bn[nt];
}

// ---------------------------------------------------------------------------
extern "C" void kernel_launch(void* const* d_in, const int* in_sizes, int n_in,
                              void* d_out, int out_size, void* d_ws,
                              size_t ws_size, hipStream_t stream) {
  const float* values = (const float*)d_in[0];
  const float* keys   = (const float*)d_in[1];
  const float* query  = (const float*)d_in[2];
  const int*   mask   = (const int*)d_in[3];
  const float* Wv     = (const float*)d_in[4];
  const float* Wk     = (const float*)d_in[5];
  const float* Wq     = (const float*)d_in[6];
  const float* Wo     = (const float*)d_in[7];
  const float* bo     = (const float*)d_in[8];
  float* out = (float*)d_out;

  short* ws = (short*)d_ws;
  const size_t tsz = (size_t)NB * NHEADS * LSEQ * HD;  // 4 Mi shorts
  short* Qb  = ws;
  short* Kb  = Qb + tsz;
  short* Vt  = Kb + tsz;
  short* AOb = Vt + tsz;
  short* Wob = AOb + tsz;                // 1 Mi shorts
  short* Wqb = Wob + (size_t)EMB * EMB;  // 4096 each
  short* Wkb = Wqb + HD * HD;
  short* Wvb = Wkb + HD * HD;

  dim3 blk(256);
  conv_kernel<<<dim3(1024), blk, 0, stream>>>(Wq, Wk, Wv, Wo, Wqb, Wkb, Wvb,
                                              Wob);
  proj_mfma<<<dim3(LSEQ / 64, NB * NHEADS, 3), blk, 0, stream>>>(
      query, keys, values, Wqb, Wkb, Wvb, mask, Qb, Kb, Vt);
  attn_kernel<<<dim3(256), dim3(512), 0, stream>>>(Qb, Kb, Vt, mask, AOb);
  outproj_mfma<<<dim3(512), blk, 0, stream>>>(AOb, Wob, bo, out);
}

// Round 9
// 185.859 us; speedup vs baseline: 1.1745x; 1.0587x over previous
//
#include <hip/hip_runtime.h>
#include <hip/hip_bf16.h>
#include <cstdint>

// MultiHeadSelfAttention N=2,L=2048,E=1024,H=16,D=64.
// Round 13: consolidation composite. attn = round-9 pipelined kernel
// VERBATIM (proven 55.3us, VGPR 112, no spill): 32q/wave, dbuf XOR-swizzled
// K/V LDS, QK(t+1) MFMA overlaps SM(t) VALU, loads 2 tiles ahead, both
// per-tile barriers load-bearing (QK(t+1) reads the freshly-written buffer
// at next iteration top). non-attn = round-12 config VERBATIM (conv once;
// proj/outproj consume bf16 weights; mask-at-source).
// LESSON (r10-r12): 512-thr workgroups hard-cap at 128 arch-VGPR on this
// toolchain -> q-reuse x2 (~210-reg live set) always spills; shelved.
// Attribution: with attn at 55.3, any non-attn kernel >=56us must surface
// in top-5 next round.

#define NB 2
#define LSEQ 2048
#define EMB 1024
#define NHEADS 16
#define HD 64

// (1/sqrt(1024)) * log2(e): folded into Wq bf16 conversion; P = exp2(S)
#define QSCALE 0.045084220027780106f

using short8 = __attribute__((ext_vector_type(8))) short;
using short4v = __attribute__((ext_vector_type(4))) short;
using f32x4 = __attribute__((ext_vector_type(4))) float;
using f32x16 = __attribute__((ext_vector_type(16))) float;
using uint2v = __attribute__((ext_vector_type(2))) unsigned int;

__device__ inline short bf16of(float f) {
  union { __hip_bfloat16 b; short s; } u;
  u.b = __float2bfloat16(f);
  return u.s;
}

__device__ inline short4v pack4bf(float a, float b, float c, float d) {
  union { __hip_bfloat162 v[2]; short4v s; } u;
  u.v[0] = __float22bfloat162_rn(make_float2(a, b));
  u.v[1] = __float22bfloat162_rn(make_float2(c, d));
  return u.s;
}

__device__ inline short8 pack8bf(float4 a, float4 b) {
  union { short4v q[2]; short8 o; } u;
  u.q[0] = pack4bf(a.x, a.y, a.z, a.w);
  u.q[1] = pack4bf(b.x, b.y, b.z, b.w);
  return u.o;
}

__device__ inline unsigned pk2(float lo, float hi) {
  union { __hip_bfloat162 v; unsigned u; } x;
  x.v = __float22bfloat162_rn(make_float2(lo, hi));
  return x.u;
}

// v_permlane32_swap_b32: a' = {a.lo, b.lo}, b' = {a.hi, b.hi}
__device__ inline void plswap(unsigned& a, unsigned& b) {
#if __has_builtin(__builtin_amdgcn_permlane32_swap)
  uint2v r = __builtin_amdgcn_permlane32_swap(a, b, false, false);
  a = r[0];
  b = r[1];
#else
  asm volatile("v_permlane32_swap_b32 %0, %1" : "+v"(a), "+v"(b));
#endif
}

__device__ inline float fexp2(float x) {
#if __has_builtin(__builtin_amdgcn_exp2f)
  return __builtin_amdgcn_exp2f(x);
#else
  return exp2f(x);
#endif
}

#define MFMA(A, B, C) __builtin_amdgcn_mfma_f32_16x16x32_bf16((A), (B), (C), 0, 0, 0)
#define MFMA32(A, B, C) __builtin_amdgcn_mfma_f32_32x32x16_bf16((A), (B), (C), 0, 0, 0)

// ---------------------------------------------------------------------------
// Weight conversion only: Wo->bf16 (grid-wide), Wq(*QSCALE)/Wk/Wv->bf16
// (blocks 0-2). Mask is consumed raw by proj/attn.
__global__ __launch_bounds__(256) void conv_kernel(
    const float* __restrict__ Wq, const float* __restrict__ Wk,
    const float* __restrict__ Wv, const float* __restrict__ Wo,
    short* __restrict__ Wqb, short* __restrict__ Wkb,
    short* __restrict__ Wvb, short* __restrict__ Wob) {
  const int b = blockIdx.x, t = threadIdx.x;
  {
    int i = (b * 256 + t) * 4;  // 1024 blocks * 1024 = 1Mi elements of Wo
    float4 v = *(const float4*)&Wo[i];
    *(short4v*)&Wob[i] = pack4bf(v.x, v.y, v.z, v.w);
  }
  if (b < 3) {
    const float* src = (b == 0) ? Wq : (b == 1) ? Wk : Wv;
    short* dst = (b == 0) ? Wqb : (b == 1) ? Wkb : Wvb;
    const float sc = (b == 0) ? QSCALE : 1.0f;
#pragma unroll
    for (int i = 0; i < 4; ++i) {
      int j = t * 16 + i * 4;  // 256*16 = 4096
      float4 v = *(const float4*)&src[j];
      *(short4v*)&dst[j] = pack4bf(v.x * sc, v.y * sc, v.z * sc, v.w * sc);
    }
  }
}

// ---------------------------------------------------------------------------
// LDS-free MFMA projections, bf16 weights (pre-converted; Wqb pre-scaled).
// Block = 4 waves, 64 l-rows, one (n,h,z). z==1 (K): masked rows zeroed
// (-> S column exactly 0 -> P exactly 1). z==2 (V): masked V^T cols zeroed.
__global__ __launch_bounds__(256) void proj_mfma(
    const float* __restrict__ xq, const float* __restrict__ xk,
    const float* __restrict__ xv, const short* __restrict__ Wqb,
    const short* __restrict__ Wkb, const short* __restrict__ Wvb,
    const int* __restrict__ mask, short* __restrict__ Qb,
    short* __restrict__ Kb, short* __restrict__ Vt) {
  const int t = threadIdx.x;
  const int wq = t >> 6, lane = t & 63;
  const int quad = lane >> 4, l15 = lane & 15;
  const int z = blockIdx.z, nh = blockIdx.y;
  const int n = nh >> 4, h = nh & 15;
  const int l0 = blockIdx.x * 64;
  const float* x = (z == 0) ? xq : (z == 1) ? xk : xv;
  const short* W = (z == 0) ? Wqb : (z == 1) ? Wkb : Wvb;
  const int lrow = l0 + wq * 16 + l15;  // this lane's l (n-index for z<2)

  // x fragment: 8 f32 -> bf16, k = e chunk c*32+quad*8
  short8 xf[2];
  const float* xr = x + ((size_t)n * LSEQ + lrow) * EMB + h * HD;
#pragma unroll
  for (int c = 0; c < 2; ++c) {
    float4 a = *(const float4*)(xr + c * 32 + quad * 8);
    float4 b = *(const float4*)(xr + c * 32 + quad * 8 + 4);
    xf[c] = pack8bf(a, b);
  }
  // W fragments: row (mt*16+l15) of W[d][e] (A for z<2; B=W^T for z==2)
  short8 wf[4][2];
#pragma unroll
  for (int mt = 0; mt < 4; ++mt)
#pragma unroll
    for (int c = 0; c < 2; ++c)
      wf[mt][c] = *(const short8*)(W + (mt * 16 + l15) * HD + c * 32 + quad * 8);

  f32x4 acc[4];
#pragma unroll
  for (int a = 0; a < 4; ++a) acc[a] = (f32x4){0.f, 0.f, 0.f, 0.f};

  if (z < 2) {
#pragma unroll
    for (int c = 0; c < 2; ++c)
#pragma unroll
      for (int mt = 0; mt < 4; ++mt) acc[mt] = MFMA(wf[mt][c], xf[c], acc[mt]);
    // K: zero masked rows at the source (Q: QSCALE already in Wqb)
    const float mk =
        (z == 1) ? (mask[n * LSEQ + lrow] ? 1.0f : 0.0f) : 1.0f;
    short* ob = ((z == 0) ? Qb : Kb) + ((size_t)nh * LSEQ + lrow) * HD;
#pragma unroll
    for (int mt = 0; mt < 4; ++mt)
      *(short4v*)&ob[mt * 16 + quad * 4] =
          pack4bf(acc[mt][0] * mk, acc[mt][1] * mk, acc[mt][2] * mk,
                  acc[mt][3] * mk);
  } else {
#pragma unroll
    for (int c = 0; c < 2; ++c)
#pragma unroll
      for (int nt = 0; nt < 4; ++nt) acc[nt] = MFMA(xf[c], wf[nt][c], acc[nt]);
    // C rows = l = l0 + wq*16 + quad*4 + r ; cols = d = nt*16+l15
    const int4 mi = *(const int4*)(mask + n * LSEQ + l0 + wq * 16 + quad * 4);
    f32x4 mv;
    mv[0] = mi.x ? 1.f : 0.f;
    mv[1] = mi.y ? 1.f : 0.f;
    mv[2] = mi.z ? 1.f : 0.f;
    mv[3] = mi.w ? 1.f : 0.f;
#pragma unroll
    for (int nt = 0; nt < 4; ++nt)
      *(short4v*)&Vt[((size_t)nh * HD + nt * 16 + l15) * LSEQ + l0 + wq * 16 +
                     quad * 4] =
          pack4bf(acc[nt][0] * mv[0], acc[nt][1] * mv[1], acc[nt][2] * mv[2],
                  acc[nt][3] * mv[3]);
  }
}

// ---------------------------------------------------------------------------
// Flash attention, 32x32 MFMA, double-buffered XOR-swizzled K/V LDS,
// 2-STAGE PIPELINE: at iteration t the wave issues QK(t+1) MFMAs first
// (K(t+1) already in LDS), overlapping SM(t)'s VALU; PV(t) follows. Global
// loads fetch tile t+2 (written into the buffer freed by PV(t)).
// Block = 4 waves = 128 q; grid 512 XCD-grouped -> 2 blocks/CU.
// Masked K rows / V cols are zero at source -> masked P == 1 exactly;
// l corrected by nmask (computed here from raw mask). Zero bias path.
// NOTE: both per-tile barriers are required -- QK(t+2) reads the buffer
// written at the end of iteration t at the TOP of iteration t+1.
__global__ __launch_bounds__(256, 2) void attn_kernel(
    const short* __restrict__ Qg,   // [nh][L][64] bf16 (Wq pre-scaled)
    const short* __restrict__ Kg,   // [nh][L][64] bf16 (masked rows zero)
    const short* __restrict__ Vtg,  // [nh][64][L] bf16 (masked cols zero)
    const int* __restrict__ mask,   // [N][L]
    short* __restrict__ AO)         // [N*L][E] bf16
{
  __shared__ __align__(16) short Ks[2][64 * 64];
  __shared__ __align__(16) short Vs[2][64 * 64];

  const int t = threadIdx.x;
  const int wv = t >> 6, lane = t & 63;
  const int l31 = lane & 31, hi = lane >> 5;

  // XCD-grouped swizzle: 512 blocks, 64/XCD; nh = xcd*4 + (idx>>4).
  const int raw = blockIdx.x;
  const int xcd = raw & 7, idx = raw >> 3;
  const int nh = (xcd << 2) | (idx >> 4);
  const int q0 = (idx & 15) * 128;
  const int n = nh >> 4, h = nh & 15;

  // nmask: count of masked (==0) keys for this n (per-wave redundant)
  float nm = 0.f;
  {
    const int* mp = mask + n * LSEQ + lane * 32;
#pragma unroll
    for (int i = 0; i < 8; ++i) {
      int4 m = *(const int4*)(mp + i * 4);
      nm += (float)((m.x == 0) + (m.y == 0) + (m.z == 0) + (m.w == 0));
    }
#pragma unroll
    for (int o = 1; o < 64; o <<= 1) nm += __shfl_xor(nm, o);
  }

  // Q B-fragments: q = q0 + wv*32 + l31, d = s*16 + hi*8 + j (resident)
  short8 qf[4];
  {
    const short* qr =
        Qg + ((size_t)nh * LSEQ + q0 + wv * 32 + l31) * HD + hi * 8;
#pragma unroll
    for (int s = 0; s < 4; ++s) qf[s] = *(const short8*)(qr + s * 16);
  }

  const short* kbase = Kg + (size_t)nh * LSEQ * HD;
  const short* vbase = Vtg + (size_t)nh * HD * LSEQ;

  // staging: 512 16B slots/tile; thread covers rows t>>3 and (t>>3)+32
  const int r0s = t >> 3, cs = t & 7, r1s = r0s + 32;
  const int ld0 = r0s * 64 + ((cs ^ (r0s & 7)) * 8);
  const int ld1 = r1s * 64 + ((cs ^ (r1s & 7)) * 8);

  {  // prologue: stage tiles 0 and 1
    short8 k0 = *(const short8*)(kbase + (size_t)r0s * HD + cs * 8);
    short8 k1 = *(const short8*)(kbase + (size_t)r1s * HD + cs * 8);
    short8 v0 = *(const short8*)(vbase + (size_t)r0s * LSEQ + cs * 8);
    short8 v1 = *(const short8*)(vbase + (size_t)r1s * LSEQ + cs * 8);
    const short* kb = kbase + (size_t)64 * HD;
    const short* vb = vbase + 64;
    short8 k2 = *(const short8*)(kb + (size_t)r0s * HD + cs * 8);
    short8 k3 = *(const short8*)(kb + (size_t)r1s * HD + cs * 8);
    short8 v2 = *(const short8*)(vb + (size_t)r0s * LSEQ + cs * 8);
    short8 v3 = *(const short8*)(vb + (size_t)r1s * LSEQ + cs * 8);
    *(short8*)&Ks[0][ld0] = k0;
    *(short8*)&Ks[0][ld1] = k1;
    *(short8*)&Vs[0][ld0] = v0;
    *(short8*)&Vs[0][ld1] = v1;
    *(short8*)&Ks[1][ld0] = k2;
    *(short8*)&Ks[1][ld1] = k3;
    *(short8*)&Vs[1][ld0] = v2;
    *(short8*)&Vs[1][ld1] = v3;
  }
  __syncthreads();

  f32x16 O[2];
#pragma unroll
  for (int nt = 0; nt < 2; ++nt)
#pragma unroll
    for (int r = 0; r < 16; ++r) O[nt][r] = 0.f;
  float ls[4] = {0.f, 0.f, 0.f, 0.f};

  f32x16 StA[2], StB[2];

  // QK(0) -> StA (tile 0 from buffer 0)
#pragma unroll
  for (int g = 0; g < 2; ++g) {
#pragma unroll
    for (int r = 0; r < 16; ++r) StA[g][r] = 0.f;
    const int row = g * 32 + l31;
#pragma unroll
    for (int s = 0; s < 4; ++s) {
      short8 kf = *(const short8*)(&Ks[0][0] + row * 64 +
                                   (((s * 2 + hi) ^ (row & 7)) * 8));
      StA[g] = MFMA32(kf, qf[s], StA[g]);
    }
  }

#define NT (LSEQ / 64)

  // step: Sc = scores(t) ready; computes QK(t+1)->Sn, SM(t), PV(t);
  // loads tile t+2 and writes it into buffer (t&1) after PV(t).
  auto step = [&](f32x16(&Sc)[2], f32x16(&Sn)[2], int tt) {
    const bool haveNext = (tt + 1 < NT);
    const bool haveLd = (tt + 2 < NT);
    short8 kr0, kr1, vr0, vr1;
    if (haveLd) {
      const short* kb = kbase + (size_t)(tt + 2) * 64 * HD;
      const short* vb = vbase + (tt + 2) * 64;
      kr0 = *(const short8*)(kb + (size_t)r0s * HD + cs * 8);
      kr1 = *(const short8*)(kb + (size_t)r1s * HD + cs * 8);
      vr0 = *(const short8*)(vb + (size_t)r0s * LSEQ + cs * 8);
      vr1 = *(const short8*)(vb + (size_t)r1s * LSEQ + cs * 8);
    }

    // ---- QK(t+1) [MFMA] first: fills matrix pipe, overlaps SM(t) VALU
    if (haveNext) {
      const short* ksb = &Ks[(tt + 1) & 1][0];
      __builtin_amdgcn_s_setprio(1);
#pragma unroll
      for (int g = 0; g < 2; ++g) {
#pragma unroll
        for (int r = 0; r < 16; ++r) Sn[g][r] = 0.f;
        const int row = g * 32 + l31;
#pragma unroll
        for (int s = 0; s < 4; ++s) {
          short8 kf = *(const short8*)(ksb + row * 64 +
                                       (((s * 2 + hi) ^ (row & 7)) * 8));
          Sn[g] = MFMA32(kf, qf[s], Sn[g]);
        }
      }
      __builtin_amdgcn_s_setprio(0);
    }

    // ---- SM(t): P = exp2(Sc); in-register row-sum (q = l31)
#pragma unroll
    for (int g = 0; g < 2; ++g)
#pragma unroll
      for (int r = 0; r < 16; ++r) {
        float e = fexp2(Sc[g][r]);
        Sc[g][r] = e;
        ls[r & 3] += e;
      }

    // ---- repack Sc (C layout) -> A-fragments pa[s] (k = s*16 + hi*8 + j)
    short8 pa[4];
#pragma unroll
    for (int g = 0; g < 2; ++g)
#pragma unroll
      for (int hf = 0; hf < 2; ++hf) {
        unsigned w0 = pk2(Sc[g][hf * 8 + 0], Sc[g][hf * 8 + 1]);
        unsigned w2 = pk2(Sc[g][hf * 8 + 4], Sc[g][hf * 8 + 5]);
        plswap(w0, w2);
        unsigned w1 = pk2(Sc[g][hf * 8 + 2], Sc[g][hf * 8 + 3]);
        unsigned w3 = pk2(Sc[g][hf * 8 + 6], Sc[g][hf * 8 + 7]);
        plswap(w1, w3);
        union { unsigned u[4]; short8 s; } uo;
        uo.u[0] = w0;
        uo.u[1] = w1;
        uo.u[2] = w2;
        uo.u[3] = w3;
        pa[g * 2 + hf] = uo.s;
      }

    // ---- PV(t) (A = P, B = V^T rows = d) from buffer (t&1)
    {
      const short* vsb = &Vs[tt & 1][0];
      __builtin_amdgcn_s_setprio(1);
#pragma unroll
      for (int s = 0; s < 4; ++s) {
#pragma unroll
        for (int nt = 0; nt < 2; ++nt) {
          const int row = nt * 32 + l31;
          short8 vf = *(const short8*)(vsb + row * 64 +
                                       (((s * 2 + hi) ^ (row & 7)) * 8));
          O[nt] = MFMA32(pa[s], vf, O[nt]);
        }
      }
      __builtin_amdgcn_s_setprio(0);
    }

    // ---- recycle buffer (t&1) with tile t+2
    if (tt < NT - 1) {
      __syncthreads();  // all waves done reading K(t)/V(t)
      if (haveLd) {
        short* kd = &Ks[tt & 1][0];
        short* vd = &Vs[tt & 1][0];
        *(short8*)&kd[ld0] = kr0;
        *(short8*)&kd[ld1] = kr1;
        *(short8*)&vd[ld0] = vr0;
        *(short8*)&vd[ld1] = vr1;
      }
      __syncthreads();  // buffer ready for QK(t+2) next iteration
    }
  };

#pragma unroll 1
  for (int ii = 0; ii < NT / 2; ++ii) {
    step(StA, StB, 2 * ii);
    step(StB, StA, 2 * ii + 1);
  }
#undef NT

  // ---- epilogue: l (masked keys contributed exactly 1 each -> subtract)
  float lsum = (ls[0] + ls[1]) + (ls[2] + ls[3]);
  lsum += __shfl_xor(lsum, 32);
  const float linv = 1.0f / (lsum - nm);
  short* ob = AO + ((size_t)n * LSEQ + q0 + wv * 32) * EMB + h * HD;
#pragma unroll
  for (int r = 0; r < 16; ++r) {
    const int qr = (r & 3) + 8 * (r >> 2) + 4 * hi;
    float li = __int_as_float(
        __builtin_amdgcn_ds_bpermute(qr << 2, __float_as_int(linv)));
    ob[(size_t)qr * EMB + l31] = bf16of(O[0][r] * li);
    ob[(size_t)qr * EMB + 32 + l31] = bf16of(O[1][r] * li);
  }
}

// ---------------------------------------------------------------------------
// Out-projection: C[r][j] = sum_e A[r][e]*Wo[j][e] + bo[j], bf16 Wob
// (pre-converted by conv -- no f32 conversion in the inner loop).
// 128x64 tile/block, grid 512, XCD-grouped by r-block. XOR-swizzled LDS,
// double-buffered, register prefetch.
__global__ __launch_bounds__(256, 2) void outproj_mfma(
    const short* __restrict__ A, const short* __restrict__ W,
    const float* __restrict__ bo, float* __restrict__ C) {
  __shared__ __align__(16) short As[2][128 * 64];
  __shared__ __align__(16) short Bs[2][64 * 64];
  const int t = threadIdx.x;
  const int wq = t >> 6, lane = t & 63;
  const int quad = lane >> 4, l15 = lane & 15;
  // XCD-grouped: 512 blocks, 64/XCD; ry = xcd*4 + (idx>>4), jx = idx&15.
  const int raw = blockIdx.x;
  const int xcd = raw & 7, idx = raw >> 3;
  const int ry = (xcd << 2) | (idx >> 4);
  const int j0 = (idx & 15) * 64, r0 = ry * 128;

  f32x4 acc[2][4];
#pragma unroll
  for (int a = 0; a < 2; ++a)
#pragma unroll
    for (int b = 0; b < 4; ++b) acc[a][b] = (f32x4){0.f, 0.f, 0.f, 0.f};

  // A: 1024 slots (row = slot>>3, ch = slot&7); B: 512 slots.
  short8 ar[4], br[2];
#pragma unroll
  for (int i = 0; i < 4; ++i) {
    int slot = i * 256 + t, row = slot >> 3, ch = slot & 7;
    ar[i] = *(const short8*)(A + (size_t)(r0 + row) * EMB + ch * 8);
  }
#pragma unroll
  for (int i = 0; i < 2; ++i) {
    int slot = i * 256 + t, row = slot >> 3, ch = slot & 7;
    br[i] = *(const short8*)(W + (size_t)(j0 + row) * EMB + ch * 8);
  }
#pragma unroll
  for (int i = 0; i < 4; ++i) {
    int slot = i * 256 + t, row = slot >> 3, ch = slot & 7;
    *(short8*)&As[0][row * 64 + ((ch ^ (row & 7)) * 8)] = ar[i];
  }
#pragma unroll
  for (int i = 0; i < 2; ++i) {
    int slot = i * 256 + t, row = slot >> 3, ch = slot & 7;
    *(short8*)&Bs[0][row * 64 + ((ch ^ (row & 7)) * 8)] = br[i];
  }
  __syncthreads();

  const int sw0 = ((0 * 4 + quad) ^ (l15 & 7)) * 8;
  const int sw1 = ((1 * 4 + quad) ^ (l15 & 7)) * 8;

  for (int ek = 0; ek < EMB; ek += 64) {
    const int cur = (ek >> 6) & 1, nxt = cur ^ 1;
    if (ek + 64 < EMB) {
#pragma unroll
      for (int i = 0; i < 4; ++i) {
        int slot = i * 256 + t, row = slot >> 3, ch = slot & 7;
        ar[i] = *(const short8*)(A + (size_t)(r0 + row) * EMB + ek + 64 + ch * 8);
      }
#pragma unroll
      for (int i = 0; i < 2; ++i) {
        int slot = i * 256 + t, row = slot >> 3, ch = slot & 7;
        br[i] = *(const short8*)(W + (size_t)(j0 + row) * EMB + ek + 64 + ch * 8);
      }
    }
#pragma unroll
    for (int c = 0; c < 2; ++c) {
      const int sw = c ? sw1 : sw0;
      short8 af[2], bf[4];
#pragma unroll
      for (int mt = 0; mt < 2; ++mt)
        af[mt] = *(const short8*)&As[cur][(wq * 32 + mt * 16 + l15) * 64 + sw];
#pragma unroll
      for (int nt = 0; nt < 4; ++nt)
        bf[nt] = *(const short8*)&Bs[cur][(nt * 16 + l15) * 64 + sw];
#pragma unroll
      for (int mt = 0; mt < 2; ++mt)
#pragma unroll
        for (int nt = 0; nt < 4; ++nt)
          acc[mt][nt] = MFMA(af[mt], bf[nt], acc[mt][nt]);
    }
    if (ek + 64 < EMB) {
#pragma unroll
      for (int i = 0; i < 4; ++i) {
        int slot = i * 256 + t, row = slot >> 3, ch = slot & 7;
        *(short8*)&As[nxt][row * 64 + ((ch ^ (row & 7)) * 8)] = ar[i];
      }
#pragma unroll
      for (int i = 0; i < 2; ++i) {
        int slot = i * 256 + t, row = slot >> 3, ch = slot & 7;
        *(short8*)&Bs[nxt][row * 64 + ((ch ^ (row & 7)) * 8)] = br[i];
      }
    }
    __syncthreads();
  }

  float bn[4];
#pragma unroll
  for (int nt = 0; nt < 4; ++nt) bn[nt] = bo[j0 + nt * 16 + l15];
#pragma unroll
  for (int mt = 0; mt < 2; ++mt)
#pragma unroll
    for (int nt = 0; nt < 4; ++nt)
#pragma unroll
      for (int r = 0; r < 4; ++r)
        C[(size_t)(r0 + wq * 32 + mt * 16 + quad * 4 + r) * EMB + j0 +
          nt * 16 + l15] = acc[mt][nt][r] + bn[nt];
}

// ---------------------------------------------------------------------------
extern "C" void kernel_launch(void* const* d_in, const int* in_sizes, int n_in,
                              void* d_out, int out_size, void* d_ws,
                              size_t ws_size, hipStream_t stream) {
  const float* values = (const float*)d_in[0];
  const float* keys   = (const float*)d_in[1];
  const float* query  = (const float*)d_in[2];
  const int*   mask   = (const int*)d_in[3];
  const float* Wv     = (const float*)d_in[4];
  const float* Wk     = (const float*)d_in[5];
  const float* Wq     = (const float*)d_in[6];
  const float* Wo     = (const float*)d_in[7];
  const float* bo     = (const float*)d_in[8];
  float* out = (float*)d_out;

  short* ws = (short*)d_ws;
  const size_t tsz = (size_t)NB * NHEADS * LSEQ * HD;  // 4 Mi shorts
  short* Qb  = ws;
  short* Kb  = Qb + tsz;
  short* Vt  = Kb + tsz;
  short* AOb = Vt + tsz;
  short* Wob = AOb + tsz;                // 1 Mi shorts
  short* Wqb = Wob + (size_t)EMB * EMB;  // 4096 each
  short* Wkb = Wqb + HD * HD;
  short* Wvb = Wkb + HD * HD;

  dim3 blk(256);
  conv_kernel<<<dim3(1024), blk, 0, stream>>>(Wq, Wk, Wv, Wo, Wqb, Wkb, Wvb,
                                              Wob);
  proj_mfma<<<dim3(LSEQ / 64, NB * NHEADS, 3), blk, 0, stream>>>(
      query, keys, values, Wqb, Wkb, Wvb, mask, Qb, Kb, Vt);
  attn_kernel<<<dim3(512), blk, 0, stream>>>(Qb, Kb, Vt, mask, AOb);
  outproj_mfma<<<dim3(512), blk, 0, stream>>>(AOb, Wob, bo, out);
}